// Round 10
// baseline (270.680 us; speedup 1.0000x reference)
//
#include <hip/hip_runtime.h>
#include <hip/hip_bf16.h>
#include <math.h>

#define BATCH   2
#define SEQLEN  2048
#define DMODEL  1024
#define DINNER  2048
#define DSTATE  16
#define NHEADS  8
#define HEADDIM 256
#define DXBC    2080
#define NPACK   6184   // packed cols: 4096 interleaved z0/x0 + 2080 xBC + 8 dt
#define NPAD    6400   // padded to 256
#define NPADX   2304   // zx2 width: xBC (2080) + dt (8) + pad
#define MROWS   4096   // BATCH*SEQLEN
#define CHUNK   64
#define NCHUNK  32
#define BH      16

typedef unsigned int u32;
typedef unsigned short u16;
typedef __attribute__((ext_vector_type(8))) short short8;
typedef __attribute__((ext_vector_type(4))) float f32x4;

#define GLOAD16(g, l) __builtin_amdgcn_global_load_lds( \
    (const __attribute__((address_space(1))) u32*)(g),  \
    (__attribute__((address_space(3))) u32*)(l), 16, 0, 0)

#define MFMA_B16(d, a, b) d = __builtin_amdgcn_mfma_f32_16x16x32_bf16(a, b, d, 0, 0, 0)

__device__ __forceinline__ u16 f2bf(float f) {
  union { float f; u32 u; } v; v.f = f;
  u32 r = v.u + 0x7fff + ((v.u >> 16) & 1);
  return (u16)(r >> 16);
}
__device__ __forceinline__ float bf2f(u16 b) {
  union { u32 u; float f; } v; v.u = ((u32)b) << 16;
  return v.f;
}

struct GParts { float* p0; float* p1; };

// ---------------- fused conversions ----------------
// W_in packing: packed col j<4096: orig row (j>>1) + (j&1)*2048  (z0/x0
// interleaved so gemmA's epilogue can fuse mlp_skip via lane-pair shfl);
// j in [4096,NPACK): orig row j+2048 (xBC + dt; skips unused 4096..6143).
#define S_U   1048576           // MROWS*DMODEL/4
#define S_WG  1048576           // DINNER*DINNER/4
#define S_WO  1048576           // DMODEL*2*DINNER/4
#define S_WP  1638400           // NPAD*256
#define S_TOT (S_U + S_WG + S_WO + S_WP)

__global__ void cvt_all(const float* __restrict__ u, const float* __restrict__ Wg,
                        const float* __restrict__ Wo, const float* __restrict__ Win,
                        u16* __restrict__ ub, u16* __restrict__ Wgb,
                        u16* __restrict__ Wob, u16* __restrict__ Wp) {
  for (int i = blockIdx.x * 256 + threadIdx.x; i < S_TOT; i += gridDim.x * 256) {
    const float* src; u16* dst; int idx;
    if (i < S_U) { src = u; dst = ub; idx = i; }
    else if (i < S_U + S_WG) { src = Wg; dst = Wgb; idx = i - S_U; }
    else if (i < S_U + S_WG + S_WO) { src = Wo; dst = Wob; idx = i - S_U - S_WG; }
    else {
      int j = i - S_U - S_WG - S_WO;
      int row = j >> 8, c4 = j & 255;
      ushort4 o = make_ushort4(0, 0, 0, 0);
      if (row < NPACK) {
        int orig = row < 4096 ? (row >> 1) + ((row & 1) << 11) : row + 2048;
        float4 v = ((const float4*)(Win + (size_t)orig * DMODEL))[c4];
        o = make_ushort4(f2bf(v.x), f2bf(v.y), f2bf(v.z), f2bf(v.w));
      }
      ((ushort4*)Wp)[j] = o;
      continue;
    }
    float4 v = ((const float4*)src)[idx];
    ((ushort4*)dst)[idx] = make_ushort4(f2bf(v.x), f2bf(v.y), f2bf(v.z), f2bf(v.w));
  }
}

// ===================== shared GEMM building blocks =====================
// LDS row r = 128B (64 bf16), 16B granules XOR-swizzled: logical granule q of
// row r at physical q^(r&7). Linear gload_lds dest + pre-swizzled global src.
template <int NL>
__device__ __forceinline__ void stage_rows(const u16* __restrict__ gsrc, int ldk,
                                           char* ldsmat, int row0, int w, int l) {
  const int rl = w * 8 + (l >> 3);
  const int q = ((l & 7) ^ (l >> 3)) * 8;
  #pragma unroll
  for (int j = 0; j < NL; ++j) {
    GLOAD16(gsrc + (size_t)(row0 + j * 64 + rl) * ldk + q,
            ldsmat + (row0 + j * 64 + w * 8) * 128);
  }
}

__device__ __forceinline__ short8 frag8(const char* mat, int row, int q) {
  return *(const short8*)(mat + row * 128 + ((q ^ (row & 7)) << 4));
}

// ============== gemmA: 256x256 tile, BK=64, 2-buffer, 4-phase ==============
// Epilogue: by<16 (interleaved z0/x0 cols) -> mlp_skip fused via shfl-pair,
// write bf16 silu(z0)*x0 to hcat[:, :2048]. by>=16 -> bf16 to zx2 (xBC+dt).
__global__ __launch_bounds__(512, 1) void gemmA(
    const u16* __restrict__ A, const u16* __restrict__ B, int K, int ldk,
    u16* __restrict__ zx2, u16* __restrict__ hcat) {
  __shared__ char lds[131072];
  const int tid = threadIdx.x;
  const int w = tid >> 6, l = tid & 63;
  const int wm = w >> 2, wn = w & 3;
  const int fr = l & 15, g = l >> 4;
  int s = blockIdx.y * gridDim.x + blockIdx.x;
  const int nwg = gridDim.x * gridDim.y;
  s = (s & 7) * (nwg >> 3) + (s >> 3);
  const int bx = s % gridDim.x, by = s / gridDim.x;
  const u16* Ap = A + (size_t)bx * 256 * ldk;
  const u16* Bp = B + (size_t)by * 256 * ldk;
  const int NT = K >> 6;

  f32x4 acc[8][4];
  #pragma unroll
  for (int m = 0; m < 8; ++m)
    #pragma unroll
    for (int n = 0; n < 4; ++n) acc[m][n] = (f32x4){0.f, 0.f, 0.f, 0.f};

  // prologue: tile 0 into buf0, FIFO order [Bh0][Bh1][Aq0][Aq2][Aq1][Aq3]
  stage_rows<2>(Bp, ldk, lds + 32768, 0, w, l);
  stage_rows<2>(Bp, ldk, lds + 32768, 128, w, l);
  stage_rows<1>(Ap, ldk, lds, 0, w, l);
  stage_rows<1>(Ap, ldk, lds, 128, w, l);
  stage_rows<1>(Ap, ldk, lds, 64, w, l);
  stage_rows<1>(Ap, ldk, lds, 192, w, l);

  for (int t = 0; t < NT; ++t) {
    const bool last = (t == NT - 1);
    const char* cbA = lds + (t & 1) * 65536;
    const char* cbB = cbA + 32768;
    char* nbA = lds + ((t + 1) & 1) * 65536;
    char* nbB = nbA + 32768;
    const u16* An = Ap + (size_t)(t + 1) * 64;
    const u16* Bn = Bp + (size_t)(t + 1) * 64;

    asm volatile("s_waitcnt vmcnt(2)" ::: "memory");
    __builtin_amdgcn_s_barrier();
    __builtin_amdgcn_sched_barrier(0);

    short8 bf0[4], bf1[4];
    #pragma unroll
    for (int n = 0; n < 4; ++n) {
      bf0[n] = frag8(cbB, wn * 64 + n * 16 + fr, g);
      bf1[n] = frag8(cbB, wn * 64 + n * 16 + fr, 4 + g);
    }
    {  // ph0: m0,m1
      short8 a00 = frag8(cbA, wm * 128 + fr, g);
      short8 a01 = frag8(cbA, wm * 128 + fr, 4 + g);
      short8 a10 = frag8(cbA, wm * 128 + 16 + fr, g);
      short8 a11 = frag8(cbA, wm * 128 + 16 + fr, 4 + g);
      if (!last) stage_rows<2>(Bn, ldk, nbB, 0, w, l);
      __builtin_amdgcn_sched_barrier(0);
      __builtin_amdgcn_s_setprio(1);
      #pragma unroll
      for (int n = 0; n < 4; ++n) { MFMA_B16(acc[0][n], a00, bf0[n]); MFMA_B16(acc[1][n], a10, bf0[n]); }
      #pragma unroll
      for (int n = 0; n < 4; ++n) { MFMA_B16(acc[0][n], a01, bf1[n]); MFMA_B16(acc[1][n], a11, bf1[n]); }
      __builtin_amdgcn_s_setprio(0);
    }
    {  // ph1: m2,m3
      short8 a00 = frag8(cbA, wm * 128 + 32 + fr, g);
      short8 a01 = frag8(cbA, wm * 128 + 32 + fr, 4 + g);
      short8 a10 = frag8(cbA, wm * 128 + 48 + fr, g);
      short8 a11 = frag8(cbA, wm * 128 + 48 + fr, 4 + g);
      if (!last) stage_rows<2>(Bn, ldk, nbB, 128, w, l);
      __builtin_amdgcn_sched_barrier(0);
      __builtin_amdgcn_s_setprio(1);
      #pragma unroll
      for (int n = 0; n < 4; ++n) { MFMA_B16(acc[2][n], a00, bf0[n]); MFMA_B16(acc[3][n], a10, bf0[n]); }
      #pragma unroll
      for (int n = 0; n < 4; ++n) { MFMA_B16(acc[2][n], a01, bf1[n]); MFMA_B16(acc[3][n], a11, bf1[n]); }
      __builtin_amdgcn_s_setprio(0);
    }
    if (last) { asm volatile("s_waitcnt vmcnt(0)" ::: "memory"); }
    else      { asm volatile("s_waitcnt vmcnt(4)" ::: "memory"); }
    __builtin_amdgcn_s_barrier();
    __builtin_amdgcn_sched_barrier(0);
    {  // ph2: m4,m5
      short8 a00 = frag8(cbA, wm * 128 + 64 + fr, g);
      short8 a01 = frag8(cbA, wm * 128 + 64 + fr, 4 + g);
      short8 a10 = frag8(cbA, wm * 128 + 80 + fr, g);
      short8 a11 = frag8(cbA, wm * 128 + 80 + fr, 4 + g);
      if (!last) { stage_rows<1>(An, ldk, nbA, 0, w, l); stage_rows<1>(An, ldk, nbA, 128, w, l); }
      __builtin_amdgcn_sched_barrier(0);
      __builtin_amdgcn_s_setprio(1);
      #pragma unroll
      for (int n = 0; n < 4; ++n) { MFMA_B16(acc[4][n], a00, bf0[n]); MFMA_B16(acc[5][n], a10, bf0[n]); }
      #pragma unroll
      for (int n = 0; n < 4; ++n) { MFMA_B16(acc[4][n], a01, bf1[n]); MFMA_B16(acc[5][n], a11, bf1[n]); }
      __builtin_amdgcn_s_setprio(0);
    }
    {  // ph3: m6,m7
      short8 a00 = frag8(cbA, wm * 128 + 96 + fr, g);
      short8 a01 = frag8(cbA, wm * 128 + 96 + fr, 4 + g);
      short8 a10 = frag8(cbA, wm * 128 + 112 + fr, g);
      short8 a11 = frag8(cbA, wm * 128 + 112 + fr, 4 + g);
      if (!last) { stage_rows<1>(An, ldk, nbA, 64, w, l); stage_rows<1>(An, ldk, nbA, 192, w, l); }
      __builtin_amdgcn_sched_barrier(0);
      __builtin_amdgcn_s_setprio(1);
      #pragma unroll
      for (int n = 0; n < 4; ++n) { MFMA_B16(acc[6][n], a00, bf0[n]); MFMA_B16(acc[7][n], a10, bf0[n]); }
      #pragma unroll
      for (int n = 0; n < 4; ++n) { MFMA_B16(acc[6][n], a01, bf1[n]); MFMA_B16(acc[7][n], a11, bf1[n]); }
      __builtin_amdgcn_s_setprio(0);
    }
  }

  const int er = g * 4;
  #pragma unroll
  for (int m = 0; m < 8; ++m)
    #pragma unroll
    for (int n = 0; n < 4; ++n)
      #pragma unroll
      for (int j = 0; j < 4; ++j) {
        int row = bx * 256 + wm * 128 + m * 16 + er + j;
        int col = by * 256 + wn * 64 + n * 16 + fr;
        float v = acc[m][n][j];
        if (by < 16) {
          // interleaved z0/x0: even lane holds z0, odd lane x0 (same row)
          float p = __shfl_xor(v, 1);
          if ((l & 1) == 0) {
            float r = p * v / (1.f + __expf(-v));   // silu(z0)*x0
            hcat[(size_t)row * 4096 + (col >> 1)] = f2bf(r);
          }
        } else {
          zx2[(size_t)row * NPADX + (col - 4096)] = f2bf(v);
        }
      }
}

// ============== gemmB: 256x128 tile, BK=64, ring-3, 2-phase ==============
// MAP 0: generic XCD chunk swizzle. MAP 1 (grid 16x16): A-panel XCD ownership.
// EPI 1: gate epilogue; EPI 2: fp32 partial planes (split-K via blockIdx.z).
template <int EPI, int MAP>
__global__ __launch_bounds__(512, 1) void gemmB(
    const u16* __restrict__ A, const u16* __restrict__ B, int K_loop, int ldk,
    int ldo, void* __restrict__ outp, const float* __restrict__ bias,
    const u16* __restrict__ gate_in, GParts gp) {
  __shared__ char lds[3 * 49152];
  const int tid = threadIdx.x;
  const int w = tid >> 6, l = tid & 63;
  const int wm = w >> 1, wn = w & 1;
  const int fr = l & 15, g = l >> 4;
  int bx, by;
  if (MAP == 1) {
    int b = blockIdx.y * gridDim.x + blockIdx.x;
    int r = b >> 3;
    bx = 2 * (b & 7) + (r >> 4);
    by = r & 15;
  } else {
    int s = blockIdx.y * gridDim.x + blockIdx.x;
    const int nwg = gridDim.x * gridDim.y;
    s = (s & 7) * (nwg >> 3) + (s >> 3);
    bx = s % gridDim.x; by = s / gridDim.x;
  }
  const u16* Ap = A + (size_t)bx * 256 * ldk + (size_t)blockIdx.z * K_loop;
  const u16* Bp = B + (size_t)by * 128 * ldk + (size_t)blockIdx.z * K_loop;
  const int NT = K_loop >> 6;

  f32x4 acc[4][4];
  #pragma unroll
  for (int m = 0; m < 4; ++m)
    #pragma unroll
    for (int n = 0; n < 4; ++n) acc[m][n] = (f32x4){0.f, 0.f, 0.f, 0.f};

  // prologue: tiles 0,1 (6 loads each, FIFO: Bh0 Bh1 Aq0 Aq1 Aq2 Aq3)
  #pragma unroll
  for (int p = 0; p < 2; ++p) {
    char* bA = lds + p * 49152;
    char* bB = bA + 32768;
    const u16* Ak = Ap + (size_t)p * 64;
    const u16* Bk = Bp + (size_t)p * 64;
    stage_rows<1>(Bk, ldk, bB, 0, w, l);
    stage_rows<1>(Bk, ldk, bB, 64, w, l);
    stage_rows<1>(Ak, ldk, bA, 0, w, l);
    stage_rows<1>(Ak, ldk, bA, 64, w, l);
    stage_rows<1>(Ak, ldk, bA, 128, w, l);
    stage_rows<1>(Ak, ldk, bA, 192, w, l);
  }

  int cur = 0;
  for (int t = 0; t < NT; ++t) {
    const bool last = (t == NT - 1);
    const bool dostage = (t + 2 < NT);
    int st = cur + 2; if (st >= 3) st -= 3;
    const char* cbA = lds + cur * 49152;
    const char* cbB = cbA + 32768;
    char* nbA = lds + st * 49152;
    char* nbB = nbA + 32768;
    const u16* An = Ap + (size_t)(t + 2) * 64;
    const u16* Bn = Bp + (size_t)(t + 2) * 64;

    if (last) { asm volatile("s_waitcnt vmcnt(0)" ::: "memory"); }
    else      { asm volatile("s_waitcnt vmcnt(6)" ::: "memory"); }
    __builtin_amdgcn_s_barrier();
    __builtin_amdgcn_sched_barrier(0);

    short8 bf0[4], bf1[4];
    #pragma unroll
    for (int n = 0; n < 4; ++n) {
      bf0[n] = frag8(cbB, wn * 64 + n * 16 + fr, g);
      bf1[n] = frag8(cbB, wn * 64 + n * 16 + fr, 4 + g);
    }
    {  // ph0: m0,m1
      short8 a00 = frag8(cbA, wm * 64 + fr, g);
      short8 a01 = frag8(cbA, wm * 64 + fr, 4 + g);
      short8 a10 = frag8(cbA, wm * 64 + 16 + fr, g);
      short8 a11 = frag8(cbA, wm * 64 + 16 + fr, 4 + g);
      if (dostage) {
        stage_rows<1>(Bn, ldk, nbB, 0, w, l);
        stage_rows<1>(Bn, ldk, nbB, 64, w, l);
        stage_rows<1>(An, ldk, nbA, 0, w, l);
      }
      __builtin_amdgcn_sched_barrier(0);
      __builtin_amdgcn_s_setprio(1);
      #pragma unroll
      for (int n = 0; n < 4; ++n) { MFMA_B16(acc[0][n], a00, bf0[n]); MFMA_B16(acc[1][n], a10, bf0[n]); }
      #pragma unroll
      for (int n = 0; n < 4; ++n) { MFMA_B16(acc[0][n], a01, bf1[n]); MFMA_B16(acc[1][n], a11, bf1[n]); }
      __builtin_amdgcn_s_setprio(0);
    }
    {  // ph1: m2,m3
      short8 a00 = frag8(cbA, wm * 64 + 32 + fr, g);
      short8 a01 = frag8(cbA, wm * 64 + 32 + fr, 4 + g);
      short8 a10 = frag8(cbA, wm * 64 + 48 + fr, g);
      short8 a11 = frag8(cbA, wm * 64 + 48 + fr, 4 + g);
      if (dostage) {
        stage_rows<1>(An, ldk, nbA, 64, w, l);
        stage_rows<1>(An, ldk, nbA, 128, w, l);
        stage_rows<1>(An, ldk, nbA, 192, w, l);
      }
      __builtin_amdgcn_sched_barrier(0);
      __builtin_amdgcn_s_setprio(1);
      #pragma unroll
      for (int n = 0; n < 4; ++n) { MFMA_B16(acc[2][n], a00, bf0[n]); MFMA_B16(acc[3][n], a10, bf0[n]); }
      #pragma unroll
      for (int n = 0; n < 4; ++n) { MFMA_B16(acc[2][n], a01, bf1[n]); MFMA_B16(acc[3][n], a11, bf1[n]); }
      __builtin_amdgcn_s_setprio(0);
    }
    cur = cur + 1; if (cur >= 3) cur = 0;
  }

  const int er = g * 4;
  float* pp = nullptr;
  if (EPI == 2) pp = blockIdx.z == 0 ? gp.p0 : gp.p1;
  #pragma unroll
  for (int m = 0; m < 4; ++m)
    #pragma unroll
    for (int n = 0; n < 4; ++n)
      #pragma unroll
      for (int j = 0; j < 4; ++j) {
        int row = bx * 256 + wm * 64 + m * 16 + er + j;
        int col = by * 128 + wn * 64 + n * 16 + fr;
        float v = acc[m][n][j];
        if (EPI == 1) {
          float gt = 1.f / (1.f + __expf(-(v + bias[col])));
          float nv = bf2f(gate_in[(size_t)row * 2048 + col]);
          ((u16*)outp)[(size_t)row * 4096 + 2048 + col] = f2bf(gt * nv);
        } else {
          pp[(size_t)row * ldo + col] = v;
        }
      }
}

// ---------------- split-K reduce (2 planes, fp32) ----------------
__global__ void reduce2(const float* __restrict__ p0, const float* __restrict__ p1,
                        float* __restrict__ out) {
  const int n4 = MROWS * DMODEL / 4;
  for (int i = blockIdx.x * 256 + threadIdx.x; i < n4; i += gridDim.x * 256) {
    float4 a = ((const float4*)p0)[i];
    float4 b = ((const float4*)p1)[i];
    float4 o;
    o.x = a.x + b.x; o.y = a.y + b.y; o.z = a.z + b.z; o.w = a.w + b.w;
    ((float4*)out)[i] = o;
  }
}

// ---------------- fused prep: conv1d+SiLU+split | dt ----------------
#define NB_CONV 16640   // MROWS*DXBC/2/256
#define NB_DT   128     // MROWS*8/256

__global__ void prep_kernel(const u16* __restrict__ zx2, const float* __restrict__ cw,
                            const float* __restrict__ cb, u16* __restrict__ xc,
                            float* __restrict__ bc,
                            const float* __restrict__ dt_bias, float* __restrict__ dtb) {
  int blk = blockIdx.x;
  if (blk < NB_CONV) {
    int idx = blk * 256 + threadIdx.x;       // over MROWS * DXBC/2
    int c2 = idx % (DXBC / 2);
    int m = idx / (DXBC / 2);
    int c = c2 * 2;
    int l = m & (SEQLEN - 1);
    const u16* col = zx2 + (size_t)m * NPADX + c;
    float2 cbv = *(const float2*)(cb + c);
    float4 w0 = ((const float4*)cw)[c2 * 2];
    float4 w1 = ((const float4*)cw)[c2 * 2 + 1];
    float a0 = cbv.x, a1 = cbv.y;
    ushort2 t0 = *(const ushort2*)col;
    a0 += w0.w * bf2f(t0.x); a1 += w1.w * bf2f(t0.y);
    if (l >= 1) { ushort2 t = *(const ushort2*)(col - NPADX);     a0 += w0.z * bf2f(t.x); a1 += w1.z * bf2f(t.y); }
    if (l >= 2) { ushort2 t = *(const ushort2*)(col - 2 * NPADX); a0 += w0.y * bf2f(t.x); a1 += w1.y * bf2f(t.y); }
    if (l >= 3) { ushort2 t = *(const ushort2*)(col - 3 * NPADX); a0 += w0.x * bf2f(t.x); a1 += w1.x * bf2f(t.y); }
    float s0 = a0 / (1.f + __expf(-a0));
    float s1 = a1 / (1.f + __expf(-a1));
    if (c < DINNER) {
      ushort2 o; o.x = f2bf(s0); o.y = f2bf(s1);
      *(ushort2*)(xc + (size_t)m * DINNER + c) = o;
    } else {
      float2 o; o.x = s0; o.y = s1;
      *(float2*)(bc + (size_t)m * 32 + (c - DINNER)) = o;
    }
  } else {
    int idx = (blk - NB_CONV) * 256 + threadIdx.x;
    if (idx >= MROWS * NHEADS) return;
    int hd = idx & 7, m = idx >> 3;
    float raw = bf2f(zx2[(size_t)m * NPADX + 2080 + hd]) + dt_bias[hd];
    float dtv = raw > 20.f ? raw : log1pf(expf(raw));
    dtb[idx] = dtv;
  }
}

// ================= SSD chunked scan =================
__device__ __forceinline__ int xs_addr(int r, int p) {  // byte offset
  return r * 512 + ((((p >> 3) ^ ((r >> 3) & 3)) & 31) << 4) + (p & 7) * 2;
}
__device__ __forceinline__ int P_addr(int t, int s) {   // byte offset, 64x64 bf16
  return t * 128 + ((((s >> 3) ^ (t & 7)) & 7) << 4) + (s & 7) * 2;
}

__device__ __forceinline__ void stage_x(u16* xs, const u16* __restrict__ xc,
                                        size_t base, int tid) {
  #pragma unroll
  for (int it = 0; it < 8; ++it) {
    int r = it * 8 + (tid >> 5);
    int pc = (tid & 31) * 8;
    short8 v = *(const short8*)(xc + base + (size_t)r * DINNER + pc);
    *(short8*)((char*)xs + xs_addr(r, pc)) = v;
  }
}

__device__ __forceinline__ short8 xfrag(const u16* xs, int k0, int g, int p) {
  short8 v;
  #pragma unroll
  for (int j = 0; j < 8; ++j) {
    int s = k0 + g * 8 + j;
    v[j] = *(const short*)((const char*)xs + xs_addr(s, p));
  }
  return v;
}

// S1: per-(bh,chunk) state S_c[n][p] and log-decay prefix lc
__global__ __launch_bounds__(256) void ssd_state(
    const u16* __restrict__ xc, const float* __restrict__ bcb,
    const float* __restrict__ dtb, const float* __restrict__ A_log,
    float* __restrict__ Sbuf, float* __restrict__ lcbuf) {
  __shared__ u16 xs[64 * 256];
  __shared__ float sLC[64], sDT[64];
  __shared__ float wBT[16][65];
  const int tid = threadIdx.x;
  const int bh = blockIdx.x >> 5, c = blockIdx.x & 31;
  const int b = bh >> 3, h = bh & 7;
  const size_t row0 = (size_t)b * SEQLEN + c * CHUNK;
  stage_x(xs, xc, row0 * DINNER + h * HEADDIM, tid);
  if (tid < 64) {
    float dtv = dtb[(row0 + tid) * NHEADS + h];
    float A = -__expf(A_log[h]);
    float s = dtv * A;
    #pragma unroll
    for (int off = 1; off < 64; off <<= 1) {
      float v = __shfl_up(s, off, 64);
      if (tid >= off) s += v;
    }
    sLC[tid] = s; sDT[tid] = dtv;
    lcbuf[(size_t)blockIdx.x * 64 + tid] = s;
  }
  __syncthreads();
  const float lc63 = sLC[63];
  for (int i = tid; i < 1024; i += 256) {
    int n = i & 15, t = i >> 4;
    float w = sDT[t] * __expf(lc63 - sLC[t]);
    wBT[n][t] = w * bcb[(row0 + t) * 32 + n];
  }
  __syncthreads();
  const int lane = tid & 63, w = tid >> 6;
  const int cl = lane & 15, g = lane >> 4;
  f32x4 acc[4];
  #pragma unroll
  for (int pt = 0; pt < 4; ++pt) acc[pt] = (f32x4){0.f, 0.f, 0.f, 0.f};
  #pragma unroll
  for (int kk = 0; kk < 2; ++kk) {
    int k0 = kk * 32;
    short8 af;
    #pragma unroll
    for (int j = 0; j < 8; ++j) af[j] = (short)f2bf(wBT[cl][k0 + g * 8 + j]);
    #pragma unroll
    for (int pt = 0; pt < 4; ++pt) {
      short8 bf = xfrag(xs, k0, g, (w * 4 + pt) * 16 + cl);
      acc[pt] = __builtin_amdgcn_mfma_f32_16x16x32_bf16(af, bf, acc[pt], 0, 0, 0);
    }
  }
  float* Sc = Sbuf + (size_t)blockIdx.x * 16 * 256;
  #pragma unroll
  for (int pt = 0; pt < 4; ++pt)
    #pragma unroll
    for (int j = 0; j < 4; ++j)
      Sc[(g * 4 + j) * 256 + (w * 4 + pt) * 16 + cl] = acc[pt][j];
}

// S2: inter-chunk recurrence
__global__ __launch_bounds__(256) void ssd_combine(
    const float* __restrict__ Sbuf, const float* __restrict__ lcbuf,
    float* __restrict__ Sprev) {
  const int bh = blockIdx.x >> 4, seg = blockIdx.x & 15;
  const int idx = seg * 256 + threadIdx.x;   // n*256+p
  float r = 0.f;
  #pragma unroll 1
  for (int c = 0; c < NCHUNK; ++c) {
    size_t o = ((size_t)bh * NCHUNK + c) * 4096 + idx;
    Sprev[o] = r;
    float lam = __expf(lcbuf[((size_t)bh * NCHUNK + c) * 64 + 63]);
    r = lam * r + Sbuf[o];
  }
}

// S3: intra-chunk (CB^T masked) @ X + Ce @ Sprev^T + D*x -> y (bf16)
__global__ __launch_bounds__(256) void ssd_out(
    const u16* __restrict__ xc, const float* __restrict__ bcb,
    const float* __restrict__ dtb, const float* __restrict__ lcbuf,
    const float* __restrict__ Sprev, const float* __restrict__ D_par,
    u16* __restrict__ y) {
  __shared__ u16 xs[64 * 256];
  __shared__ u16 P[64 * 64];
  __shared__ u16 sB[64][17], sC[64][17], sCe[64][17];
  __shared__ u16 sSp[256][17];
  __shared__ float sLC[64], sDT[64];
  const int tid = threadIdx.x;
  const int bh = blockIdx.x >> 5, c = blockIdx.x & 31;
  const int b = bh >> 3, h = bh & 7;
  const size_t row0 = (size_t)b * SEQLEN + c * CHUNK;
  stage_x(xs, xc, row0 * DINNER + h * HEADDIM, tid);
  if (tid < 64) {
    sLC[tid] = lcbuf[(size_t)blockIdx.x * 64 + tid];
    sDT[tid] = dtb[(row0 + tid) * NHEADS + h];
  }
  for (int i = tid; i < 1024; i += 256) {
    int n = i & 15, t = i >> 4;
    float Bv = bcb[(row0 + t) * 32 + n];
    float Cv = bcb[(row0 + t) * 32 + 16 + n];
    float e = __expf(lcbuf[(size_t)blockIdx.x * 64 + t]);
    sB[t][n] = f2bf(Bv);
    sC[t][n] = f2bf(Cv);
    sCe[t][n] = f2bf(Cv * e);
  }
  {
    const float* Sp = Sprev + (size_t)blockIdx.x * 4096;
    int p = tid & 255;
    if (tid < 256) {
      #pragma unroll
      for (int n = 0; n < 16; ++n) sSp[p][n] = f2bf(Sp[n * 256 + p]);
    }
  }
  __syncthreads();

  const int lane = tid & 63, w = tid >> 6;
  const int cl = lane & 15, g = lane >> 4;

  f32x4 gacc[4];
  #pragma unroll
  for (int st = 0; st < 4; ++st) gacc[st] = (f32x4){0.f, 0.f, 0.f, 0.f};
  short8 afc = (short8){0, 0, 0, 0, 0, 0, 0, 0};
  if (g < 2) {
    #pragma unroll
    for (int j = 0; j < 8; ++j) afc[j] = (short)sC[w * 16 + cl][g * 8 + j];
  }
  #pragma unroll
  for (int st = 0; st < 4; ++st) {
    short8 bfb = (short8){0, 0, 0, 0, 0, 0, 0, 0};
    if (g < 2) {
      #pragma unroll
      for (int j = 0; j < 8; ++j) bfb[j] = (short)sB[st * 16 + cl][g * 8 + j];
    }
    gacc[st] = __builtin_amdgcn_mfma_f32_16x16x32_bf16(afc, bfb, gacc[st], 0, 0, 0);
  }
  #pragma unroll
  for (int st = 0; st < 4; ++st) {
    #pragma unroll
    for (int j = 0; j < 4; ++j) {
      int t = w * 16 + g * 4 + j;
      int s = st * 16 + cl;
      float v = 0.f;
      if (s <= t) v = gacc[st][j] * sDT[s] * __expf(sLC[t] - sLC[s]);
      *(u16*)((char*)P + P_addr(t, s)) = f2bf(v);
    }
  }
  asm volatile("s_waitcnt lgkmcnt(0)" ::: "memory");
  __builtin_amdgcn_sched_barrier(0);

  f32x4 acc[16];
  #pragma unroll
  for (int pt = 0; pt < 16; ++pt) acc[pt] = (f32x4){0.f, 0.f, 0.f, 0.f};
  #pragma unroll
  for (int kk = 0; kk < 2; ++kk) {
    int k0 = kk * 32;
    short8 ap = *(const short8*)((const char*)P + P_addr(w * 16 + cl, k0 + g * 8));
    #pragma unroll
    for (int pt = 0; pt < 16; ++pt) {
      short8 bf = xfrag(xs, k0, g, pt * 16 + cl);
      acc[pt] = __builtin_amdgcn_mfma_f32_16x16x32_bf16(ap, bf, acc[pt], 0, 0, 0);
    }
  }
  {
    short8 ae = (short8){0, 0, 0, 0, 0, 0, 0, 0};
    if (g < 2) {
      #pragma unroll
      for (int j = 0; j < 8; ++j) ae[j] = (short)sCe[w * 16 + cl][g * 8 + j];
    }
    #pragma unroll
    for (int pt = 0; pt < 16; ++pt) {
      short8 bs = (short8){0, 0, 0, 0, 0, 0, 0, 0};
      if (g < 2) {
        #pragma unroll
        for (int j = 0; j < 8; ++j) bs[j] = (short)sSp[pt * 16 + cl][g * 8 + j];
      }
      acc[pt] = __builtin_amdgcn_mfma_f32_16x16x32_bf16(ae, bs, acc[pt], 0, 0, 0);
    }
  }
  const float Dv = D_par[h];
  #pragma unroll
  for (int pt = 0; pt < 16; ++pt) {
    #pragma unroll
    for (int j = 0; j < 4; ++j) {
      int t = w * 16 + g * 4 + j;
      int p = pt * 16 + cl;
      float xv = bf2f(*(const u16*)((const char*)xs + xs_addr(t, p)));
      float v = acc[pt][j] + Dv * xv;
      y[(row0 + t) * DINNER + h * HEADDIM + p] = f2bf(v);
    }
  }
}

// ---------------- layernorm (bf16 in) -> bf16 ----------------
__global__ __launch_bounds__(256) void ln_kernel(const u16* __restrict__ y,
                                                 const float* __restrict__ gamma,
                                                 const float* __restrict__ beta,
                                                 u16* __restrict__ nrm) {
  const int row = blockIdx.x;
  const int t = threadIdx.x;
  const u16* yr = y + (size_t)row * DINNER;
  short8 v = *(const short8*)(yr + t * 8);
  float f[8];
  float s = 0.f, ss = 0.f;
  #pragma unroll
  for (int j = 0; j < 8; ++j) {
    f[j] = bf2f((u16)v[j]);
    s += f[j]; ss += f[j] * f[j];
  }
  #pragma unroll
  for (int o = 1; o < 64; o <<= 1) { s += __shfl_xor(s, o); ss += __shfl_xor(ss, o); }
  __shared__ float rs[4], rss[4];
  const int wid = t >> 6;
  if ((t & 63) == 0) { rs[wid] = s; rss[wid] = ss; }
  __syncthreads();
  s = rs[0] + rs[1] + rs[2] + rs[3];
  ss = rss[0] + rss[1] + rss[2] + rss[3];
  float mu = s * (1.f / DINNER);
  float var = ss * (1.f / DINNER) - mu * mu;
  float inv = rsqrtf(var + 1e-5f);
  float4 g0 = ((const float4*)gamma)[t * 2], g1 = ((const float4*)gamma)[t * 2 + 1];
  float4 b0 = ((const float4*)beta)[t * 2], b1 = ((const float4*)beta)[t * 2 + 1];
  short8 o;
  o[0] = (short)f2bf((f[0] - mu) * inv * g0.x + b0.x);
  o[1] = (short)f2bf((f[1] - mu) * inv * g0.y + b0.y);
  o[2] = (short)f2bf((f[2] - mu) * inv * g0.z + b0.z);
  o[3] = (short)f2bf((f[3] - mu) * inv * g0.w + b0.w);
  o[4] = (short)f2bf((f[4] - mu) * inv * g1.x + b1.x);
  o[5] = (short)f2bf((f[5] - mu) * inv * g1.y + b1.y);
  o[6] = (short)f2bf((f[6] - mu) * inv * g1.z + b1.z);
  o[7] = (short)f2bf((f[7] - mu) * inv * g1.w + b1.w);
  *(short8*)(nrm + (size_t)row * DINNER + t * 8) = o;
}

// ---------------- host ----------------
extern "C" void kernel_launch(void* const* d_in, const int* in_sizes, int n_in,
                              void* d_out, int out_size, void* d_ws, size_t ws_size,
                              hipStream_t stream) {
  (void)in_sizes; (void)n_in; (void)out_size; (void)ws_size;
  const float* u       = (const float*)d_in[0];
  const float* W_in    = (const float*)d_in[1];
  const float* conv_w  = (const float*)d_in[2];
  const float* conv_b  = (const float*)d_in[3];
  const float* dt_bias = (const float*)d_in[4];
  const float* A_log   = (const float*)d_in[5];
  const float* D_par   = (const float*)d_in[6];
  const float* ln_g    = (const float*)d_in[7];
  const float* ln_b    = (const float*)d_in[8];
  const float* W_gate  = (const float*)d_in[9];
  const float* b_gate  = (const float*)d_in[10];
  const float* W_out   = (const float*)d_in[11];
  float* out = (float*)d_out;

  size_t off = 0;
  auto take = [&](size_t bytes) -> char* {
    char* p = (char*)d_ws + off;
    off = (off + bytes + 255) & ~(size_t)255;
    return p;
  };
  u16* u16b  = (u16*)take((size_t)MROWS * DMODEL * 2);          // dead after gemmA
  u16* Wp    = (u16*)take((size_t)NPAD * DMODEL * 2);           // dead after gemmA
  u16* Wg    = (u16*)take((size_t)DINNER * DINNER * 2);         // dead after gemm1
  u16* Wo    = (u16*)take((size_t)DMODEL * 2 * DINNER * 2);
  u16* zx2   = (u16*)take((size_t)MROWS * NPADX * 2);           // 18.9 MB (xBC+dt)
  u16* xc    = (u16*)take((size_t)MROWS * DINNER * 2);          // 16.8 MB
  float* bcb = (float*)take((size_t)MROWS * 32 * 4);
  float* dtb = (float*)take((size_t)MROWS * NHEADS * 4);
  float* lcbuf = (float*)take((size_t)BH * NCHUNK * 64 * 4);
  u16* nrm   = (u16*)take((size_t)MROWS * DINNER * 2);
  u16* hcat  = (u16*)take((size_t)MROWS * 2 * DINNER * 2);

  float* Sbuf  = (float*)u16b;         // 8 MiB, exactly u16b (dead after gemmA)
  float* Sprev = (float*)Wp;           // 8.4 MB into Wp's 13.1 MB (dead)
  u16*   y     = zx2;                  // 16 MiB into zx2's 18 MiB (dead after prep)
  // gemm2 split-2 partials (16 MiB each): u16b+Wp contiguous (dead), xc (dead)
  GParts parts2;
  parts2.p0 = (float*)d_ws;
  parts2.p1 = (float*)xc;
  GParts none = {nullptr, nullptr};

  cvt_all<<<4096, 256, 0, stream>>>(u, W_gate, W_out, W_in, u16b, Wg, Wo, Wp);

  // gemm0: 256x256 tiles, grid 16x25=400; fused mlp_skip epilogue (by<16)
  gemmA<<<dim3(MROWS / 256, NPAD / 256), 512, 0, stream>>>(
      u16b, Wp, DMODEL, DMODEL, zx2, hcat);

  prep_kernel<<<NB_CONV + NB_DT, 256, 0, stream>>>(
      zx2, conv_w, conv_b, xc, bcb, dt_bias, dtb);

  ssd_state<<<BH * NCHUNK, 256, 0, stream>>>(xc, bcb, dtb, A_log, Sbuf, lcbuf);
  ssd_combine<<<BH * 16, 256, 0, stream>>>(Sbuf, lcbuf, Sprev);
  ssd_out<<<BH * NCHUNK, 256, 0, stream>>>(xc, bcb, dtb, lcbuf, Sprev, D_par, y);

  ln_kernel<<<MROWS, 256, 0, stream>>>(y, ln_g, ln_b, nrm);

  // gemm1: 256x128 tiles, ring-3, unsplit K, fused gate; grid 16x16 (MAP 1)
  gemmB<1, 1><<<dim3(MROWS / 256, DINNER / 128), 512, 0, stream>>>(
      nrm, Wg, DINNER, DINNER, 0, hcat, b_gate, nrm, none);

  // gemm2: 256x128 tiles, ring-3, split-K=2 -> fp32 partials; grid 16x8x2
  gemmB<2, 0><<<dim3(MROWS / 256, DMODEL / 128, 2), 512, 0, stream>>>(
      hcat, Wo, 2 * DINNER / 2, 2 * DINNER, DMODEL, nullptr, nullptr, nullptr, parts2);

  reduce2<<<2048, 256, 0, stream>>>(parts2.p0, parts2.p1, out);
}

// Round 11
// 242.072 us; speedup vs baseline: 1.1182x; 1.1182x over previous
//
#include <hip/hip_runtime.h>
#include <hip/hip_bf16.h>
#include <math.h>

#define BATCH   2
#define SEQLEN  2048
#define DMODEL  1024
#define DINNER  2048
#define DSTATE  16
#define NHEADS  8
#define HEADDIM 256
#define DXBC    2080
#define NPACK   6184   // used cols of in_proj: 0..4095 (z0,x0) + 6144..8231 (xBC,dt)
#define NPAD    6400   // NPACK padded to 256 (for 256-wide GEMM tiles)
#define MROWS   4096   // BATCH*SEQLEN
#define CHUNK   64
#define NCHUNK  32
#define BH      16

typedef unsigned int u32;
typedef unsigned short u16;
typedef __attribute__((ext_vector_type(8))) short short8;
typedef __attribute__((ext_vector_type(4))) float f32x4;

#define GLOAD16(g, l) __builtin_amdgcn_global_load_lds( \
    (const __attribute__((address_space(1))) u32*)(g),  \
    (__attribute__((address_space(3))) u32*)(l), 16, 0, 0)

#define MFMA_B16(d, a, b) d = __builtin_amdgcn_mfma_f32_16x16x32_bf16(a, b, d, 0, 0, 0)

__device__ __forceinline__ u16 f2bf(float f) {
  union { float f; u32 u; } v; v.f = f;
  u32 r = v.u + 0x7fff + ((v.u >> 16) & 1);
  return (u16)(r >> 16);
}
__device__ __forceinline__ float bf2f(u16 b) {
  union { u32 u; float f; } v; v.u = ((u32)b) << 16;
  return v.f;
}

struct GParts { float* p0; float* p1; };

// ---------------- fused conversions ----------------
#define S_U   1048576           // MROWS*DMODEL/4
#define S_WG  1048576           // DINNER*DINNER/4
#define S_WO  1048576           // DMODEL*2*DINNER/4
#define S_WP  1638400           // NPAD*256
#define S_TOT (S_U + S_WG + S_WO + S_WP)

__global__ void cvt_all(const float* __restrict__ u, const float* __restrict__ Wg,
                        const float* __restrict__ Wo, const float* __restrict__ Win,
                        u16* __restrict__ ub, u16* __restrict__ Wgb,
                        u16* __restrict__ Wob, u16* __restrict__ Wp) {
  for (int i = blockIdx.x * 256 + threadIdx.x; i < S_TOT; i += gridDim.x * 256) {
    const float* src; u16* dst; int idx;
    if (i < S_U) { src = u; dst = ub; idx = i; }
    else if (i < S_U + S_WG) { src = Wg; dst = Wgb; idx = i - S_U; }
    else if (i < S_U + S_WG + S_WO) { src = Wo; dst = Wob; idx = i - S_U - S_WG; }
    else {
      int j = i - S_U - S_WG - S_WO;
      int row = j >> 8, c4 = j & 255;
      ushort4 o = make_ushort4(0, 0, 0, 0);
      if (row < NPACK) {
        int orig = row < 4096 ? row : row + 2048;
        float4 v = ((const float4*)(Win + (size_t)orig * DMODEL))[c4];
        o = make_ushort4(f2bf(v.x), f2bf(v.y), f2bf(v.z), f2bf(v.w));
      }
      ((ushort4*)Wp)[j] = o;
      continue;
    }
    float4 v = ((const float4*)src)[idx];
    ((ushort4*)dst)[idx] = make_ushort4(f2bf(v.x), f2bf(v.y), f2bf(v.z), f2bf(v.w));
  }
}

// ===================== shared GEMM building blocks =====================
template <int NL>
__device__ __forceinline__ void stage_rows(const u16* __restrict__ gsrc, int ldk,
                                           char* ldsmat, int row0, int w, int l) {
  const int rl = w * 8 + (l >> 3);
  const int q = ((l & 7) ^ (l >> 3)) * 8;   // logical element offset for phys slot
  #pragma unroll
  for (int j = 0; j < NL; ++j) {
    GLOAD16(gsrc + (size_t)(row0 + j * 64 + rl) * ldk + q,
            ldsmat + (row0 + j * 64 + w * 8) * 128);
  }
}

__device__ __forceinline__ short8 frag8(const char* mat, int row, int q) {
  return *(const short8*)(mat + row * 128 + ((q ^ (row & 7)) << 4));
}

// ============== gemmA: 256x256 tile, BK=64, 2-buffer, 4-phase ==============
__global__ __launch_bounds__(512, 1) void gemmA(
    const u16* __restrict__ A, const u16* __restrict__ B, int K, int ldk,
    int ldo, u16* __restrict__ outp) {
  __shared__ char lds[131072];
  const int tid = threadIdx.x;
  const int w = tid >> 6, l = tid & 63;
  const int wm = w >> 2, wn = w & 3;
  const int fr = l & 15, g = l >> 4;
  int s = blockIdx.y * gridDim.x + blockIdx.x;
  const int nwg = gridDim.x * gridDim.y;
  s = (s & 7) * (nwg >> 3) + (s >> 3);
  const int bx = s % gridDim.x, by = s / gridDim.x;
  const u16* Ap = A + (size_t)bx * 256 * ldk;
  const u16* Bp = B + (size_t)by * 256 * ldk;
  const int NT = K >> 6;

  f32x4 acc[8][4];
  #pragma unroll
  for (int m = 0; m < 8; ++m)
    #pragma unroll
    for (int n = 0; n < 4; ++n) acc[m][n] = (f32x4){0.f, 0.f, 0.f, 0.f};

  // prologue: tile 0 into buf0, FIFO order [Bh0][Bh1][Aq0][Aq2][Aq1][Aq3]
  stage_rows<2>(Bp, ldk, lds + 32768, 0, w, l);
  stage_rows<2>(Bp, ldk, lds + 32768, 128, w, l);
  stage_rows<1>(Ap, ldk, lds, 0, w, l);
  stage_rows<1>(Ap, ldk, lds, 128, w, l);
  stage_rows<1>(Ap, ldk, lds, 64, w, l);
  stage_rows<1>(Ap, ldk, lds, 192, w, l);

  for (int t = 0; t < NT; ++t) {
    const bool last = (t == NT - 1);
    const char* cbA = lds + (t & 1) * 65536;
    const char* cbB = cbA + 32768;
    char* nbA = lds + ((t + 1) & 1) * 65536;
    char* nbB = nbA + 32768;
    const u16* An = Ap + (size_t)(t + 1) * 64;
    const u16* Bn = Bp + (size_t)(t + 1) * 64;

    asm volatile("s_waitcnt vmcnt(2)" ::: "memory");
    __builtin_amdgcn_s_barrier();
    __builtin_amdgcn_sched_barrier(0);

    short8 bf0[4], bf1[4];
    #pragma unroll
    for (int n = 0; n < 4; ++n) {
      bf0[n] = frag8(cbB, wn * 64 + n * 16 + fr, g);
      bf1[n] = frag8(cbB, wn * 64 + n * 16 + fr, 4 + g);
    }
    {  // ph0: m0,m1
      short8 a00 = frag8(cbA, wm * 128 + fr, g);
      short8 a01 = frag8(cbA, wm * 128 + fr, 4 + g);
      short8 a10 = frag8(cbA, wm * 128 + 16 + fr, g);
      short8 a11 = frag8(cbA, wm * 128 + 16 + fr, 4 + g);
      if (!last) stage_rows<2>(Bn, ldk, nbB, 0, w, l);
      __builtin_amdgcn_sched_barrier(0);
      __builtin_amdgcn_s_setprio(1);
      #pragma unroll
      for (int n = 0; n < 4; ++n) { MFMA_B16(acc[0][n], a00, bf0[n]); MFMA_B16(acc[1][n], a10, bf0[n]); }
      #pragma unroll
      for (int n = 0; n < 4; ++n) { MFMA_B16(acc[0][n], a01, bf1[n]); MFMA_B16(acc[1][n], a11, bf1[n]); }
      __builtin_amdgcn_s_setprio(0);
    }
    {  // ph1: m2,m3
      short8 a00 = frag8(cbA, wm * 128 + 32 + fr, g);
      short8 a01 = frag8(cbA, wm * 128 + 32 + fr, 4 + g);
      short8 a10 = frag8(cbA, wm * 128 + 48 + fr, g);
      short8 a11 = frag8(cbA, wm * 128 + 48 + fr, 4 + g);
      if (!last) stage_rows<2>(Bn, ldk, nbB, 128, w, l);
      __builtin_amdgcn_sched_barrier(0);
      __builtin_amdgcn_s_setprio(1);
      #pragma unroll
      for (int n = 0; n < 4; ++n) { MFMA_B16(acc[2][n], a00, bf0[n]); MFMA_B16(acc[3][n], a10, bf0[n]); }
      #pragma unroll
      for (int n = 0; n < 4; ++n) { MFMA_B16(acc[2][n], a01, bf1[n]); MFMA_B16(acc[3][n], a11, bf1[n]); }
      __builtin_amdgcn_s_setprio(0);
    }
    if (last) { asm volatile("s_waitcnt vmcnt(0)" ::: "memory"); }
    else      { asm volatile("s_waitcnt vmcnt(4)" ::: "memory"); }
    __builtin_amdgcn_s_barrier();
    __builtin_amdgcn_sched_barrier(0);
    {  // ph2: m4,m5
      short8 a00 = frag8(cbA, wm * 128 + 64 + fr, g);
      short8 a01 = frag8(cbA, wm * 128 + 64 + fr, 4 + g);
      short8 a10 = frag8(cbA, wm * 128 + 80 + fr, g);
      short8 a11 = frag8(cbA, wm * 128 + 80 + fr, 4 + g);
      if (!last) { stage_rows<1>(An, ldk, nbA, 0, w, l); stage_rows<1>(An, ldk, nbA, 128, w, l); }
      __builtin_amdgcn_sched_barrier(0);
      __builtin_amdgcn_s_setprio(1);
      #pragma unroll
      for (int n = 0; n < 4; ++n) { MFMA_B16(acc[4][n], a00, bf0[n]); MFMA_B16(acc[5][n], a10, bf0[n]); }
      #pragma unroll
      for (int n = 0; n < 4; ++n) { MFMA_B16(acc[4][n], a01, bf1[n]); MFMA_B16(acc[5][n], a11, bf1[n]); }
      __builtin_amdgcn_s_setprio(0);
    }
    {  // ph3: m6,m7
      short8 a00 = frag8(cbA, wm * 128 + 96 + fr, g);
      short8 a01 = frag8(cbA, wm * 128 + 96 + fr, 4 + g);
      short8 a10 = frag8(cbA, wm * 128 + 112 + fr, g);
      short8 a11 = frag8(cbA, wm * 128 + 112 + fr, 4 + g);
      if (!last) { stage_rows<1>(An, ldk, nbA, 64, w, l); stage_rows<1>(An, ldk, nbA, 192, w, l); }
      __builtin_amdgcn_sched_barrier(0);
      __builtin_amdgcn_s_setprio(1);
      #pragma unroll
      for (int n = 0; n < 4; ++n) { MFMA_B16(acc[6][n], a00, bf0[n]); MFMA_B16(acc[7][n], a10, bf0[n]); }
      #pragma unroll
      for (int n = 0; n < 4; ++n) { MFMA_B16(acc[6][n], a01, bf1[n]); MFMA_B16(acc[7][n], a11, bf1[n]); }
      __builtin_amdgcn_s_setprio(0);
    }
  }

  const int er = g * 4;
  #pragma unroll
  for (int m = 0; m < 8; ++m)
    #pragma unroll
    for (int n = 0; n < 4; ++n)
      #pragma unroll
      for (int j = 0; j < 4; ++j) {
        int row = bx * 256 + wm * 128 + m * 16 + er + j;
        int col = by * 256 + wn * 64 + n * 16 + fr;
        outp[(size_t)row * ldo + col] = f2bf(acc[m][n][j]);
      }
}

// ============== gemmB: 256x128 tile, BK=64, ring-3, 2-phase ==============
// MAP 0: generic XCD chunk swizzle. MAP 1 (grid 16x16): A-panel XCD ownership.
// EPI 1: gate epilogue; EPI 2: fp32 partial planes (split-K via blockIdx.z).
template <int EPI, int MAP>
__global__ __launch_bounds__(512, 1) void gemmB(
    const u16* __restrict__ A, const u16* __restrict__ B, int K_loop, int ldk,
    int ldo, void* __restrict__ outp, const float* __restrict__ bias,
    const u16* __restrict__ gate_in, GParts gp) {
  __shared__ char lds[3 * 49152];
  const int tid = threadIdx.x;
  const int w = tid >> 6, l = tid & 63;
  const int wm = w >> 1, wn = w & 1;
  const int fr = l & 15, g = l >> 4;
  int bx, by;
  if (MAP == 1) {
    int b = blockIdx.y * gridDim.x + blockIdx.x;
    int r = b >> 3;
    bx = 2 * (b & 7) + (r >> 4);
    by = r & 15;
  } else {
    int s = blockIdx.y * gridDim.x + blockIdx.x;
    const int nwg = gridDim.x * gridDim.y;
    s = (s & 7) * (nwg >> 3) + (s >> 3);
    bx = s % gridDim.x; by = s / gridDim.x;
  }
  const u16* Ap = A + (size_t)bx * 256 * ldk + (size_t)blockIdx.z * K_loop;
  const u16* Bp = B + (size_t)by * 128 * ldk + (size_t)blockIdx.z * K_loop;
  const int NT = K_loop >> 6;

  f32x4 acc[4][4];
  #pragma unroll
  for (int m = 0; m < 4; ++m)
    #pragma unroll
    for (int n = 0; n < 4; ++n) acc[m][n] = (f32x4){0.f, 0.f, 0.f, 0.f};

  // prologue: tiles 0,1 (6 loads each, FIFO: Bh0 Bh1 Aq0 Aq1 Aq2 Aq3)
  #pragma unroll
  for (int p = 0; p < 2; ++p) {
    char* bA = lds + p * 49152;
    char* bB = bA + 32768;
    const u16* Ak = Ap + (size_t)p * 64;
    const u16* Bk = Bp + (size_t)p * 64;
    stage_rows<1>(Bk, ldk, bB, 0, w, l);
    stage_rows<1>(Bk, ldk, bB, 64, w, l);
    stage_rows<1>(Ak, ldk, bA, 0, w, l);
    stage_rows<1>(Ak, ldk, bA, 64, w, l);
    stage_rows<1>(Ak, ldk, bA, 128, w, l);
    stage_rows<1>(Ak, ldk, bA, 192, w, l);
  }

  int cur = 0;
  for (int t = 0; t < NT; ++t) {
    const bool last = (t == NT - 1);
    const bool dostage = (t + 2 < NT);
    int st = cur + 2; if (st >= 3) st -= 3;
    const char* cbA = lds + cur * 49152;
    const char* cbB = cbA + 32768;
    char* nbA = lds + st * 49152;
    char* nbB = nbA + 32768;
    const u16* An = Ap + (size_t)(t + 2) * 64;
    const u16* Bn = Bp + (size_t)(t + 2) * 64;

    if (last) { asm volatile("s_waitcnt vmcnt(0)" ::: "memory"); }
    else      { asm volatile("s_waitcnt vmcnt(6)" ::: "memory"); }
    __builtin_amdgcn_s_barrier();
    __builtin_amdgcn_sched_barrier(0);

    short8 bf0[4], bf1[4];
    #pragma unroll
    for (int n = 0; n < 4; ++n) {
      bf0[n] = frag8(cbB, wn * 64 + n * 16 + fr, g);
      bf1[n] = frag8(cbB, wn * 64 + n * 16 + fr, 4 + g);
    }
    {  // ph0: m0,m1
      short8 a00 = frag8(cbA, wm * 64 + fr, g);
      short8 a01 = frag8(cbA, wm * 64 + fr, 4 + g);
      short8 a10 = frag8(cbA, wm * 64 + 16 + fr, g);
      short8 a11 = frag8(cbA, wm * 64 + 16 + fr, 4 + g);
      if (dostage) {
        stage_rows<1>(Bn, ldk, nbB, 0, w, l);
        stage_rows<1>(Bn, ldk, nbB, 64, w, l);
        stage_rows<1>(An, ldk, nbA, 0, w, l);
      }
      __builtin_amdgcn_sched_barrier(0);
      __builtin_amdgcn_s_setprio(1);
      #pragma unroll
      for (int n = 0; n < 4; ++n) { MFMA_B16(acc[0][n], a00, bf0[n]); MFMA_B16(acc[1][n], a10, bf0[n]); }
      #pragma unroll
      for (int n = 0; n < 4; ++n) { MFMA_B16(acc[0][n], a01, bf1[n]); MFMA_B16(acc[1][n], a11, bf1[n]); }
      __builtin_amdgcn_s_setprio(0);
    }
    {  // ph1: m2,m3
      short8 a00 = frag8(cbA, wm * 64 + 32 + fr, g);
      short8 a01 = frag8(cbA, wm * 64 + 32 + fr, 4 + g);
      short8 a10 = frag8(cbA, wm * 64 + 48 + fr, g);
      short8 a11 = frag8(cbA, wm * 64 + 48 + fr, 4 + g);
      if (dostage) {
        stage_rows<1>(An, ldk, nbA, 64, w, l);
        stage_rows<1>(An, ldk, nbA, 128, w, l);
        stage_rows<1>(An, ldk, nbA, 192, w, l);
      }
      __builtin_amdgcn_sched_barrier(0);
      __builtin_amdgcn_s_setprio(1);
      #pragma unroll
      for (int n = 0; n < 4; ++n) { MFMA_B16(acc[2][n], a00, bf0[n]); MFMA_B16(acc[3][n], a10, bf0[n]); }
      #pragma unroll
      for (int n = 0; n < 4; ++n) { MFMA_B16(acc[2][n], a01, bf1[n]); MFMA_B16(acc[3][n], a11, bf1[n]); }
      __builtin_amdgcn_s_setprio(0);
    }
    cur = cur + 1; if (cur >= 3) cur = 0;
  }

  const int er = g * 4;
  float* pp = nullptr;
  if (EPI == 2) pp = blockIdx.z == 0 ? gp.p0 : gp.p1;
  #pragma unroll
  for (int m = 0; m < 4; ++m)
    #pragma unroll
    for (int n = 0; n < 4; ++n)
      #pragma unroll
      for (int j = 0; j < 4; ++j) {
        int row = bx * 256 + wm * 64 + m * 16 + er + j;
        int col = by * 128 + wn * 64 + n * 16 + fr;
        float v = acc[m][n][j];
        if (EPI == 1) {
          float gt = 1.f / (1.f + __expf(-(v + bias[col])));
          float nv = bf2f(gate_in[(size_t)row * 2048 + col]);
          ((u16*)outp)[(size_t)row * 4096 + 2048 + col] = f2bf(gt * nv);
        } else {
          pp[(size_t)row * ldo + col] = v;
        }
      }
}

// ---------------- split-K reduce (2 planes, fp32) ----------------
__global__ void reduce2(const float* __restrict__ p0, const float* __restrict__ p1,
                        float* __restrict__ out) {
  const int n4 = MROWS * DMODEL / 4;
  for (int i = blockIdx.x * 256 + threadIdx.x; i < n4; i += gridDim.x * 256) {
    float4 a = ((const float4*)p0)[i];
    float4 b = ((const float4*)p1)[i];
    float4 o;
    o.x = a.x + b.x; o.y = a.y + b.y; o.z = a.z + b.z; o.w = a.w + b.w;
    ((float4*)out)[i] = o;
  }
}

// ---------------- fused prep: conv1d+SiLU+split | mlp_skip | dt ----------------
#define NB_CONV 16640   // MROWS*DXBC/2/256
#define NB_MLP  8192    // MROWS*512/256
#define NB_DT   128     // MROWS*8/256

__global__ void prep_kernel(const u16* __restrict__ zx, const float* __restrict__ cw,
                            const float* __restrict__ cb, u16* __restrict__ xc,
                            float* __restrict__ bc, u16* __restrict__ hcat,
                            const float* __restrict__ dt_bias, float* __restrict__ dtb) {
  int blk = blockIdx.x;
  if (blk < NB_CONV) {
    int idx = blk * 256 + threadIdx.x;       // over MROWS * DXBC/2
    int c2 = idx % (DXBC / 2);
    int m = idx / (DXBC / 2);
    int c = c2 * 2;
    int l = m & (SEQLEN - 1);
    const u16* col = zx + (size_t)m * NPAD + 4096 + c;
    float2 cbv = *(const float2*)(cb + c);
    float4 w0 = ((const float4*)cw)[c2 * 2];
    float4 w1 = ((const float4*)cw)[c2 * 2 + 1];
    float a0 = cbv.x, a1 = cbv.y;
    ushort2 t0 = *(const ushort2*)col;
    a0 += w0.w * bf2f(t0.x); a1 += w1.w * bf2f(t0.y);
    if (l >= 1) { ushort2 t = *(const ushort2*)(col - NPAD);     a0 += w0.z * bf2f(t.x); a1 += w1.z * bf2f(t.y); }
    if (l >= 2) { ushort2 t = *(const ushort2*)(col - 2 * NPAD); a0 += w0.y * bf2f(t.x); a1 += w1.y * bf2f(t.y); }
    if (l >= 3) { ushort2 t = *(const ushort2*)(col - 3 * NPAD); a0 += w0.x * bf2f(t.x); a1 += w1.x * bf2f(t.y); }
    float s0 = a0 / (1.f + __expf(-a0));
    float s1 = a1 / (1.f + __expf(-a1));
    if (c < DINNER) {
      ushort2 o; o.x = f2bf(s0); o.y = f2bf(s1);
      *(ushort2*)(xc + (size_t)m * DINNER + c) = o;
    } else {
      float2 o; o.x = s0; o.y = s1;
      *(float2*)(bc + (size_t)m * 32 + (c - DINNER)) = o;
    }
  } else if (blk < NB_CONV + NB_MLP) {
    int i = (blk - NB_CONV) * 256 + threadIdx.x;
    int m = i >> 9, c4 = (i & 511) * 4;
    const u16* row = zx + (size_t)m * NPAD;
    ushort4 zv = *(const ushort4*)(row + c4);
    ushort4 xv = *(const ushort4*)(row + 2048 + c4);
    float z0, x0;
    ushort4 o;
    z0 = bf2f(zv.x); x0 = bf2f(xv.x); o.x = f2bf(x0 * z0 / (1.f + __expf(-z0)));
    z0 = bf2f(zv.y); x0 = bf2f(xv.y); o.y = f2bf(x0 * z0 / (1.f + __expf(-z0)));
    z0 = bf2f(zv.z); x0 = bf2f(xv.z); o.z = f2bf(x0 * z0 / (1.f + __expf(-z0)));
    z0 = bf2f(zv.w); x0 = bf2f(xv.w); o.w = f2bf(x0 * z0 / (1.f + __expf(-z0)));
    *(ushort4*)(hcat + (size_t)m * 4096 + c4) = o;
  } else {
    int idx = (blk - NB_CONV - NB_MLP) * 256 + threadIdx.x;
    if (idx >= MROWS * NHEADS) return;
    int hd = idx & 7, m = idx >> 3;
    float raw = bf2f(zx[(size_t)m * NPAD + 6176 + hd]) + dt_bias[hd];
    float dtv = raw > 20.f ? raw : log1pf(expf(raw));
    dtb[idx] = dtv;
  }
}

// ================= SSD chunked scan =================
__device__ __forceinline__ int xs_addr(int r, int p) {  // byte offset
  return r * 512 + ((((p >> 3) ^ ((r >> 3) & 3)) & 31) << 4) + (p & 7) * 2;
}
__device__ __forceinline__ int P_addr(int t, int s) {   // byte offset, 64x64 bf16
  return t * 128 + ((((s >> 3) ^ (t & 7)) & 7) << 4) + (s & 7) * 2;
}

__device__ __forceinline__ void stage_x(u16* xs, const u16* __restrict__ xc,
                                        size_t base, int tid) {
  #pragma unroll
  for (int it = 0; it < 8; ++it) {
    int r = it * 8 + (tid >> 5);
    int pc = (tid & 31) * 8;
    short8 v = *(const short8*)(xc + base + (size_t)r * DINNER + pc);
    *(short8*)((char*)xs + xs_addr(r, pc)) = v;
  }
}

__device__ __forceinline__ short8 xfrag(const u16* xs, int k0, int g, int p) {
  short8 v;
  #pragma unroll
  for (int j = 0; j < 8; ++j) {
    int s = k0 + g * 8 + j;
    v[j] = *(const short*)((const char*)xs + xs_addr(s, p));
  }
  return v;
}

// S1: per-(bh,chunk) state S_c[n][p] and log-decay prefix lc
__global__ __launch_bounds__(256) void ssd_state(
    const u16* __restrict__ xc, const float* __restrict__ bcb,
    const float* __restrict__ dtb, const float* __restrict__ A_log,
    float* __restrict__ Sbuf, float* __restrict__ lcbuf) {
  __shared__ u16 xs[64 * 256];
  __shared__ float sLC[64], sDT[64];
  __shared__ float wBT[16][65];
  const int tid = threadIdx.x;
  const int bh = blockIdx.x >> 5, c = blockIdx.x & 31;
  const int b = bh >> 3, h = bh & 7;
  const size_t row0 = (size_t)b * SEQLEN + c * CHUNK;
  stage_x(xs, xc, row0 * DINNER + h * HEADDIM, tid);
  if (tid < 64) {
    float dtv = dtb[(row0 + tid) * NHEADS + h];
    float A = -__expf(A_log[h]);
    float s = dtv * A;
    #pragma unroll
    for (int off = 1; off < 64; off <<= 1) {
      float v = __shfl_up(s, off, 64);
      if (tid >= off) s += v;
    }
    sLC[tid] = s; sDT[tid] = dtv;
    lcbuf[(size_t)blockIdx.x * 64 + tid] = s;
  }
  __syncthreads();
  const float lc63 = sLC[63];
  for (int i = tid; i < 1024; i += 256) {
    int n = i & 15, t = i >> 4;
    float w = sDT[t] * __expf(lc63 - sLC[t]);
    wBT[n][t] = w * bcb[(row0 + t) * 32 + n];
  }
  __syncthreads();
  const int lane = tid & 63, w = tid >> 6;
  const int cl = lane & 15, g = lane >> 4;
  f32x4 acc[4];
  #pragma unroll
  for (int pt = 0; pt < 4; ++pt) acc[pt] = (f32x4){0.f, 0.f, 0.f, 0.f};
  #pragma unroll
  for (int kk = 0; kk < 2; ++kk) {
    int k0 = kk * 32;
    short8 af;
    #pragma unroll
    for (int j = 0; j < 8; ++j) af[j] = (short)f2bf(wBT[cl][k0 + g * 8 + j]);
    #pragma unroll
    for (int pt = 0; pt < 4; ++pt) {
      short8 bf = xfrag(xs, k0, g, (w * 4 + pt) * 16 + cl);
      acc[pt] = __builtin_amdgcn_mfma_f32_16x16x32_bf16(af, bf, acc[pt], 0, 0, 0);
    }
  }
  float* Sc = Sbuf + (size_t)blockIdx.x * 16 * 256;
  #pragma unroll
  for (int pt = 0; pt < 4; ++pt)
    #pragma unroll
    for (int j = 0; j < 4; ++j)
      Sc[(g * 4 + j) * 256 + (w * 4 + pt) * 16 + cl] = acc[pt][j];
}

// S2: inter-chunk recurrence, software-pipelined (all 32 loads independent)
__global__ __launch_bounds__(256) void ssd_combine(
    const float* __restrict__ Sbuf, const float* __restrict__ lcbuf,
    float* __restrict__ Sprev) {
  const int bh = blockIdx.x >> 4, seg = blockIdx.x & 15;
  const int idx = seg * 256 + threadIdx.x;   // n*256+p
  float lam[NCHUNK], sv[NCHUNK];
  const size_t base = (size_t)bh * NCHUNK * 4096 + idx;
  #pragma unroll
  for (int c = 0; c < NCHUNK; ++c) {
    lam[c] = lcbuf[((size_t)bh * NCHUNK + c) * 64 + 63];
    sv[c] = Sbuf[base + (size_t)c * 4096];
  }
  #pragma unroll
  for (int c = 0; c < NCHUNK; ++c) lam[c] = __expf(lam[c]);
  float r = 0.f;
  #pragma unroll
  for (int c = 0; c < NCHUNK; ++c) {
    Sprev[base + (size_t)c * 4096] = r;
    r = lam[c] * r + sv[c];
  }
}

// S3: intra-chunk (CB^T masked) @ X + Ce @ Sprev^T + D*x -> y (bf16)
__global__ __launch_bounds__(256) void ssd_out(
    const u16* __restrict__ xc, const float* __restrict__ bcb,
    const float* __restrict__ dtb, const float* __restrict__ lcbuf,
    const float* __restrict__ Sprev, const float* __restrict__ D_par,
    u16* __restrict__ y) {
  __shared__ u16 xs[64 * 256];
  __shared__ u16 P[64 * 64];
  __shared__ u16 sB[64][17], sC[64][17], sCe[64][17];
  __shared__ u16 sSp[256][17];
  __shared__ float sLC[64], sDT[64];
  const int tid = threadIdx.x;
  const int bh = blockIdx.x >> 5, c = blockIdx.x & 31;
  const int b = bh >> 3, h = bh & 7;
  const size_t row0 = (size_t)b * SEQLEN + c * CHUNK;
  stage_x(xs, xc, row0 * DINNER + h * HEADDIM, tid);
  if (tid < 64) {
    sLC[tid] = lcbuf[(size_t)blockIdx.x * 64 + tid];
    sDT[tid] = dtb[(row0 + tid) * NHEADS + h];
  }
  for (int i = tid; i < 1024; i += 256) {
    int n = i & 15, t = i >> 4;
    float Bv = bcb[(row0 + t) * 32 + n];
    float Cv = bcb[(row0 + t) * 32 + 16 + n];
    float e = __expf(lcbuf[(size_t)blockIdx.x * 64 + t]);
    sB[t][n] = f2bf(Bv);
    sC[t][n] = f2bf(Cv);
    sCe[t][n] = f2bf(Cv * e);
  }
  {
    const float* Sp = Sprev + (size_t)blockIdx.x * 4096;
    int p = tid & 255;
    if (tid < 256) {
      #pragma unroll
      for (int n = 0; n < 16; ++n) sSp[p][n] = f2bf(Sp[n * 256 + p]);
    }
  }
  __syncthreads();

  const int lane = tid & 63, w = tid >> 6;
  const int cl = lane & 15, g = lane >> 4;

  f32x4 gacc[4];
  #pragma unroll
  for (int st = 0; st < 4; ++st) gacc[st] = (f32x4){0.f, 0.f, 0.f, 0.f};
  short8 afc = (short8){0, 0, 0, 0, 0, 0, 0, 0};
  if (g < 2) {
    #pragma unroll
    for (int j = 0; j < 8; ++j) afc[j] = (short)sC[w * 16 + cl][g * 8 + j];
  }
  #pragma unroll
  for (int st = 0; st < 4; ++st) {
    short8 bfb = (short8){0, 0, 0, 0, 0, 0, 0, 0};
    if (g < 2) {
      #pragma unroll
      for (int j = 0; j < 8; ++j) bfb[j] = (short)sB[st * 16 + cl][g * 8 + j];
    }
    gacc[st] = __builtin_amdgcn_mfma_f32_16x16x32_bf16(afc, bfb, gacc[st], 0, 0, 0);
  }
  #pragma unroll
  for (int st = 0; st < 4; ++st) {
    #pragma unroll
    for (int j = 0; j < 4; ++j) {
      int t = w * 16 + g * 4 + j;
      int s = st * 16 + cl;
      float v = 0.f;
      if (s <= t) v = gacc[st][j] * sDT[s] * __expf(sLC[t] - sLC[s]);
      *(u16*)((char*)P + P_addr(t, s)) = f2bf(v);
    }
  }
  asm volatile("s_waitcnt lgkmcnt(0)" ::: "memory");
  __builtin_amdgcn_sched_barrier(0);

  f32x4 acc[16];
  #pragma unroll
  for (int pt = 0; pt < 16; ++pt) acc[pt] = (f32x4){0.f, 0.f, 0.f, 0.f};
  #pragma unroll
  for (int kk = 0; kk < 2; ++kk) {
    int k0 = kk * 32;
    short8 ap = *(const short8*)((const char*)P + P_addr(w * 16 + cl, k0 + g * 8));
    #pragma unroll
    for (int pt = 0; pt < 16; ++pt) {
      short8 bf = xfrag(xs, k0, g, pt * 16 + cl);
      acc[pt] = __builtin_amdgcn_mfma_f32_16x16x32_bf16(ap, bf, acc[pt], 0, 0, 0);
    }
  }
  {
    short8 ae = (short8){0, 0, 0, 0, 0, 0, 0, 0};
    if (g < 2) {
      #pragma unroll
      for (int j = 0; j < 8; ++j) ae[j] = (short)sCe[w * 16 + cl][g * 8 + j];
    }
    #pragma unroll
    for (int pt = 0; pt < 16; ++pt) {
      short8 bs = (short8){0, 0, 0, 0, 0, 0, 0, 0};
      if (g < 2) {
        #pragma unroll
        for (int j = 0; j < 8; ++j) bs[j] = (short)sSp[pt * 16 + cl][g * 8 + j];
      }
      acc[pt] = __builtin_amdgcn_mfma_f32_16x16x32_bf16(ae, bs, acc[pt], 0, 0, 0);
    }
  }
  const float Dv = D_par[h];
  #pragma unroll
  for (int pt = 0; pt < 16; ++pt) {
    #pragma unroll
    for (int j = 0; j < 4; ++j) {
      int t = w * 16 + g * 4 + j;
      int p = pt * 16 + cl;
      float xv = bf2f(*(const u16*)((const char*)xs + xs_addr(t, p)));
      float v = acc[pt][j] + Dv * xv;
      y[(row0 + t) * DINNER + h * HEADDIM + p] = f2bf(v);
    }
  }
}

// ---------------- layernorm (bf16 in) -> bf16 ----------------
__global__ __launch_bounds__(256) void ln_kernel(const u16* __restrict__ y,
                                                 const float* __restrict__ gamma,
                                                 const float* __restrict__ beta,
                                                 u16* __restrict__ nrm) {
  const int row = blockIdx.x;
  const int t = threadIdx.x;
  const u16* yr = y + (size_t)row * DINNER;
  short8 v = *(const short8*)(yr + t * 8);
  float f[8];
  float s = 0.f, ss = 0.f;
  #pragma unroll
  for (int j = 0; j < 8; ++j) {
    f[j] = bf2f((u16)v[j]);
    s += f[j]; ss += f[j] * f[j];
  }
  #pragma unroll
  for (int o = 1; o < 64; o <<= 1) { s += __shfl_xor(s, o); ss += __shfl_xor(ss, o); }
  __shared__ float rs[4], rss[4];
  const int wid = t >> 6;
  if ((t & 63) == 0) { rs[wid] = s; rss[wid] = ss; }
  __syncthreads();
  s = rs[0] + rs[1] + rs[2] + rs[3];
  ss = rss[0] + rss[1] + rss[2] + rss[3];
  float mu = s * (1.f / DINNER);
  float var = ss * (1.f / DINNER) - mu * mu;
  float inv = rsqrtf(var + 1e-5f);
  float4 g0 = ((const float4*)gamma)[t * 2], g1 = ((const float4*)gamma)[t * 2 + 1];
  float4 b0 = ((const float4*)beta)[t * 2], b1 = ((const float4*)beta)[t * 2 + 1];
  short8 o;
  o[0] = (short)f2bf((f[0] - mu) * inv * g0.x + b0.x);
  o[1] = (short)f2bf((f[1] - mu) * inv * g0.y + b0.y);
  o[2] = (short)f2bf((f[2] - mu) * inv * g0.z + b0.z);
  o[3] = (short)f2bf((f[3] - mu) * inv * g0.w + b0.w);
  o[4] = (short)f2bf((f[4] - mu) * inv * g1.x + b1.x);
  o[5] = (short)f2bf((f[5] - mu) * inv * g1.y + b1.y);
  o[6] = (short)f2bf((f[6] - mu) * inv * g1.z + b1.z);
  o[7] = (short)f2bf((f[7] - mu) * inv * g1.w + b1.w);
  *(short8*)(nrm + (size_t)row * DINNER + t * 8) = o;
}

// ---------------- host ----------------
extern "C" void kernel_launch(void* const* d_in, const int* in_sizes, int n_in,
                              void* d_out, int out_size, void* d_ws, size_t ws_size,
                              hipStream_t stream) {
  (void)in_sizes; (void)n_in; (void)out_size; (void)ws_size;
  const float* u       = (const float*)d_in[0];
  const float* W_in    = (const float*)d_in[1];
  const float* conv_w  = (const float*)d_in[2];
  const float* conv_b  = (const float*)d_in[3];
  const float* dt_bias = (const float*)d_in[4];
  const float* A_log   = (const float*)d_in[5];
  const float* D_par   = (const float*)d_in[6];
  const float* ln_g    = (const float*)d_in[7];
  const float* ln_b    = (const float*)d_in[8];
  const float* W_gate  = (const float*)d_in[9];
  const float* b_gate  = (const float*)d_in[10];
  const float* W_out   = (const float*)d_in[11];
  float* out = (float*)d_out;

  size_t off = 0;
  auto take = [&](size_t bytes) -> char* {
    char* p = (char*)d_ws + off;
    off = (off + bytes + 255) & ~(size_t)255;
    return p;
  };
  u16* u16b  = (u16*)take((size_t)MROWS * DMODEL * 2);          // dead after gemmA
  u16* Wp    = (u16*)take((size_t)NPAD * DMODEL * 2);           // dead after gemmA
  u16* Wg    = (u16*)take((size_t)DINNER * DINNER * 2);         // dead after gemm1
  u16* Wo    = (u16*)take((size_t)DMODEL * 2 * DINNER * 2);
  u16* zx    = (u16*)take((size_t)MROWS * NPAD * 2);            // 52.4 MB
  u16* xc    = (u16*)take((size_t)MROWS * DINNER * 2);
  float* bcb = (float*)take((size_t)MROWS * 32 * 4);
  float* dtb = (float*)take((size_t)MROWS * NHEADS * 4);
  float* lcbuf = (float*)take((size_t)BH * NCHUNK * 64 * 4);
  u16* nrm   = (u16*)take((size_t)MROWS * DINNER * 2);
  u16* hcat  = (u16*)take((size_t)MROWS * 2 * DINNER * 2);

  float* Sbuf  = (float*)u16b;                                   // 8 MB (u16b dead)
  u16*   y     = zx;                                             // 16 MB
  float* Sprev = (float*)((char*)zx + (size_t)16 * 1024 * 1024); // 8 MB
  // gemm2 split-2 partials (16 MB each) over dead zx region
  GParts parts2;
  parts2.p0 = (float*)zx;
  parts2.p1 = (float*)((char*)zx + (size_t)16 * 1024 * 1024);
  GParts none = {nullptr, nullptr};

  cvt_all<<<4096, 256, 0, stream>>>(u, W_gate, W_out, W_in, u16b, Wg, Wo, Wp);

  // gemm0: 256x256 tiles, grid 16x25=400
  gemmA<<<dim3(MROWS / 256, NPAD / 256), 512, 0, stream>>>(
      u16b, Wp, DMODEL, DMODEL, NPAD, zx);

  prep_kernel<<<NB_CONV + NB_MLP + NB_DT, 256, 0, stream>>>(
      zx, conv_w, conv_b, xc, bcb, hcat, dt_bias, dtb);

  ssd_state<<<BH * NCHUNK, 256, 0, stream>>>(xc, bcb, dtb, A_log, Sbuf, lcbuf);
  ssd_combine<<<BH * 16, 256, 0, stream>>>(Sbuf, lcbuf, Sprev);
  ssd_out<<<BH * NCHUNK, 256, 0, stream>>>(xc, bcb, dtb, lcbuf, Sprev, D_par, y);

  ln_kernel<<<MROWS, 256, 0, stream>>>(y, ln_g, ln_b, nrm);

  // gemm1: 256x128 tiles, ring-3, unsplit K, fused gate; grid 16x16 (MAP 1)
  gemmB<1, 1><<<dim3(MROWS / 256, DINNER / 128), 512, 0, stream>>>(
      nrm, Wg, DINNER, DINNER, 0, hcat, b_gate, nrm, none);

  // gemm2: 256x128 tiles, ring-3, split-K=2 -> fp32 partials; grid 16x8x2
  gemmB<2, 0><<<dim3(MROWS / 256, DMODEL / 128, 2), 512, 0, stream>>>(
      hcat, Wo, 2 * DINNER / 2, 2 * DINNER, DMODEL, nullptr, nullptr, nullptr, parts2);

  reduce2<<<2048, 256, 0, stream>>>(parts2.p0, parts2.p1, out);
}

// Round 12
// 231.679 us; speedup vs baseline: 1.1683x; 1.0449x over previous
//
#include <hip/hip_runtime.h>
#include <hip/hip_bf16.h>
#include <math.h>

#define BATCH   2
#define SEQLEN  2048
#define DMODEL  1024
#define DINNER  2048
#define DSTATE  16
#define NHEADS  8
#define HEADDIM 256
#define DXBC    2080
#define NPACK   6184   // used cols of in_proj: 0..4095 (z0,x0) + 6144..8231 (xBC,dt)
#define NPAD    6400   // NPACK padded to 256 (for 256-wide GEMM tiles)
#define MROWS   4096   // BATCH*SEQLEN
#define CHUNK   64
#define NCHUNK  32
#define BH      16

typedef unsigned int u32;
typedef unsigned short u16;
typedef __attribute__((ext_vector_type(8))) short short8;
typedef __attribute__((ext_vector_type(4))) float f32x4;

#define GLOAD16(g, l) __builtin_amdgcn_global_load_lds( \
    (const __attribute__((address_space(1))) u32*)(g),  \
    (__attribute__((address_space(3))) u32*)(l), 16, 0, 0)

#define MFMA_B16(d, a, b) d = __builtin_amdgcn_mfma_f32_16x16x32_bf16(a, b, d, 0, 0, 0)

__device__ __forceinline__ u16 f2bf(float f) {
  union { float f; u32 u; } v; v.f = f;
  u32 r = v.u + 0x7fff + ((v.u >> 16) & 1);
  return (u16)(r >> 16);
}
__device__ __forceinline__ float bf2f(u16 b) {
  union { u32 u; float f; } v; v.u = ((u32)b) << 16;
  return v.f;
}

// ---------------- fused conversions ----------------
#define S_U   1048576           // MROWS*DMODEL/4
#define S_WG  1048576           // DINNER*DINNER/4
#define S_WO  1048576           // DMODEL*2*DINNER/4
#define S_WP  1638400           // NPAD*256
#define S_TOT (S_U + S_WG + S_WO + S_WP)

__global__ void cvt_all(const float* __restrict__ u, const float* __restrict__ Wg,
                        const float* __restrict__ Wo, const float* __restrict__ Win,
                        u16* __restrict__ ub, u16* __restrict__ Wgb,
                        u16* __restrict__ Wob, u16* __restrict__ Wp) {
  for (int i = blockIdx.x * 256 + threadIdx.x; i < S_TOT; i += gridDim.x * 256) {
    const float* src; u16* dst; int idx;
    if (i < S_U) { src = u; dst = ub; idx = i; }
    else if (i < S_U + S_WG) { src = Wg; dst = Wgb; idx = i - S_U; }
    else if (i < S_U + S_WG + S_WO) { src = Wo; dst = Wob; idx = i - S_U - S_WG; }
    else {
      int j = i - S_U - S_WG - S_WO;
      int row = j >> 8, c4 = j & 255;
      ushort4 o = make_ushort4(0, 0, 0, 0);
      if (row < NPACK) {
        int orig = row < 4096 ? row : row + 2048;
        float4 v = ((const float4*)(Win + (size_t)orig * DMODEL))[c4];
        o = make_ushort4(f2bf(v.x), f2bf(v.y), f2bf(v.z), f2bf(v.w));
      }
      ((ushort4*)Wp)[j] = o;
      continue;
    }
    float4 v = ((const float4*)src)[idx];
    ((ushort4*)dst)[idx] = make_ushort4(f2bf(v.x), f2bf(v.y), f2bf(v.z), f2bf(v.w));
  }
}

// ===================== shared GEMM building blocks =====================
template <int NL>
__device__ __forceinline__ void stage_rows(const u16* __restrict__ gsrc, int ldk,
                                           char* ldsmat, int row0, int w, int l) {
  const int rl = w * 8 + (l >> 3);
  const int q = ((l & 7) ^ (l >> 3)) * 8;   // logical element offset for phys slot
  #pragma unroll
  for (int j = 0; j < NL; ++j) {
    GLOAD16(gsrc + (size_t)(row0 + j * 64 + rl) * ldk + q,
            ldsmat + (row0 + j * 64 + w * 8) * 128);
  }
}

__device__ __forceinline__ short8 frag8(const char* mat, int row, int q) {
  return *(const short8*)(mat + row * 128 + ((q ^ (row & 7)) << 4));
}

// ============== gemmA: 256x256 tile, BK=64, 2-buffer, 4-phase ==============
__global__ __launch_bounds__(512, 1) void gemmA(
    const u16* __restrict__ A, const u16* __restrict__ B, int K, int ldk,
    int ldo, u16* __restrict__ outp) {
  __shared__ char lds[131072];
  const int tid = threadIdx.x;
  const int w = tid >> 6, l = tid & 63;
  const int wm = w >> 2, wn = w & 3;
  const int fr = l & 15, g = l >> 4;
  int s = blockIdx.y * gridDim.x + blockIdx.x;
  const int nwg = gridDim.x * gridDim.y;
  s = (s & 7) * (nwg >> 3) + (s >> 3);
  const int bx = s % gridDim.x, by = s / gridDim.x;
  const u16* Ap = A + (size_t)bx * 256 * ldk;
  const u16* Bp = B + (size_t)by * 256 * ldk;
  const int NT = K >> 6;

  f32x4 acc[8][4];
  #pragma unroll
  for (int m = 0; m < 8; ++m)
    #pragma unroll
    for (int n = 0; n < 4; ++n) acc[m][n] = (f32x4){0.f, 0.f, 0.f, 0.f};

  // prologue: tile 0 into buf0, FIFO order [Bh0][Bh1][Aq0][Aq2][Aq1][Aq3]
  stage_rows<2>(Bp, ldk, lds + 32768, 0, w, l);
  stage_rows<2>(Bp, ldk, lds + 32768, 128, w, l);
  stage_rows<1>(Ap, ldk, lds, 0, w, l);
  stage_rows<1>(Ap, ldk, lds, 128, w, l);
  stage_rows<1>(Ap, ldk, lds, 64, w, l);
  stage_rows<1>(Ap, ldk, lds, 192, w, l);

  for (int t = 0; t < NT; ++t) {
    const bool last = (t == NT - 1);
    const char* cbA = lds + (t & 1) * 65536;
    const char* cbB = cbA + 32768;
    char* nbA = lds + ((t + 1) & 1) * 65536;
    char* nbB = nbA + 32768;
    const u16* An = Ap + (size_t)(t + 1) * 64;
    const u16* Bn = Bp + (size_t)(t + 1) * 64;

    asm volatile("s_waitcnt vmcnt(2)" ::: "memory");
    __builtin_amdgcn_s_barrier();
    __builtin_amdgcn_sched_barrier(0);

    short8 bf0[4], bf1[4];
    #pragma unroll
    for (int n = 0; n < 4; ++n) {
      bf0[n] = frag8(cbB, wn * 64 + n * 16 + fr, g);
      bf1[n] = frag8(cbB, wn * 64 + n * 16 + fr, 4 + g);
    }
    {  // ph0: m0,m1
      short8 a00 = frag8(cbA, wm * 128 + fr, g);
      short8 a01 = frag8(cbA, wm * 128 + fr, 4 + g);
      short8 a10 = frag8(cbA, wm * 128 + 16 + fr, g);
      short8 a11 = frag8(cbA, wm * 128 + 16 + fr, 4 + g);
      if (!last) stage_rows<2>(Bn, ldk, nbB, 0, w, l);
      __builtin_amdgcn_sched_barrier(0);
      __builtin_amdgcn_s_setprio(1);
      #pragma unroll
      for (int n = 0; n < 4; ++n) { MFMA_B16(acc[0][n], a00, bf0[n]); MFMA_B16(acc[1][n], a10, bf0[n]); }
      #pragma unroll
      for (int n = 0; n < 4; ++n) { MFMA_B16(acc[0][n], a01, bf1[n]); MFMA_B16(acc[1][n], a11, bf1[n]); }
      __builtin_amdgcn_s_setprio(0);
    }
    {  // ph1: m2,m3
      short8 a00 = frag8(cbA, wm * 128 + 32 + fr, g);
      short8 a01 = frag8(cbA, wm * 128 + 32 + fr, 4 + g);
      short8 a10 = frag8(cbA, wm * 128 + 48 + fr, g);
      short8 a11 = frag8(cbA, wm * 128 + 48 + fr, 4 + g);
      if (!last) stage_rows<2>(Bn, ldk, nbB, 128, w, l);
      __builtin_amdgcn_sched_barrier(0);
      __builtin_amdgcn_s_setprio(1);
      #pragma unroll
      for (int n = 0; n < 4; ++n) { MFMA_B16(acc[2][n], a00, bf0[n]); MFMA_B16(acc[3][n], a10, bf0[n]); }
      #pragma unroll
      for (int n = 0; n < 4; ++n) { MFMA_B16(acc[2][n], a01, bf1[n]); MFMA_B16(acc[3][n], a11, bf1[n]); }
      __builtin_amdgcn_s_setprio(0);
    }
    if (last) { asm volatile("s_waitcnt vmcnt(0)" ::: "memory"); }
    else      { asm volatile("s_waitcnt vmcnt(4)" ::: "memory"); }
    __builtin_amdgcn_s_barrier();
    __builtin_amdgcn_sched_barrier(0);
    {  // ph2: m4,m5
      short8 a00 = frag8(cbA, wm * 128 + 64 + fr, g);
      short8 a01 = frag8(cbA, wm * 128 + 64 + fr, 4 + g);
      short8 a10 = frag8(cbA, wm * 128 + 80 + fr, g);
      short8 a11 = frag8(cbA, wm * 128 + 80 + fr, 4 + g);
      if (!last) { stage_rows<1>(An, ldk, nbA, 0, w, l); stage_rows<1>(An, ldk, nbA, 128, w, l); }
      __builtin_amdgcn_sched_barrier(0);
      __builtin_amdgcn_s_setprio(1);
      #pragma unroll
      for (int n = 0; n < 4; ++n) { MFMA_B16(acc[4][n], a00, bf0[n]); MFMA_B16(acc[5][n], a10, bf0[n]); }
      #pragma unroll
      for (int n = 0; n < 4; ++n) { MFMA_B16(acc[4][n], a01, bf1[n]); MFMA_B16(acc[5][n], a11, bf1[n]); }
      __builtin_amdgcn_s_setprio(0);
    }
    {  // ph3: m6,m7
      short8 a00 = frag8(cbA, wm * 128 + 96 + fr, g);
      short8 a01 = frag8(cbA, wm * 128 + 96 + fr, 4 + g);
      short8 a10 = frag8(cbA, wm * 128 + 112 + fr, g);
      short8 a11 = frag8(cbA, wm * 128 + 112 + fr, 4 + g);
      if (!last) { stage_rows<1>(An, ldk, nbA, 64, w, l); stage_rows<1>(An, ldk, nbA, 192, w, l); }
      __builtin_amdgcn_sched_barrier(0);
      __builtin_amdgcn_s_setprio(1);
      #pragma unroll
      for (int n = 0; n < 4; ++n) { MFMA_B16(acc[6][n], a00, bf0[n]); MFMA_B16(acc[7][n], a10, bf0[n]); }
      #pragma unroll
      for (int n = 0; n < 4; ++n) { MFMA_B16(acc[6][n], a01, bf1[n]); MFMA_B16(acc[7][n], a11, bf1[n]); }
      __builtin_amdgcn_s_setprio(0);
    }
  }

  const int er = g * 4;
  #pragma unroll
  for (int m = 0; m < 8; ++m)
    #pragma unroll
    for (int n = 0; n < 4; ++n)
      #pragma unroll
      for (int j = 0; j < 4; ++j) {
        int row = bx * 256 + wm * 128 + m * 16 + er + j;
        int col = by * 256 + wn * 64 + n * 16 + fr;
        outp[(size_t)row * ldo + col] = f2bf(acc[m][n][j]);
      }
}

// ============== gemmB: 256x128 tile, BK=64, ring-3, 2-phase ==============
// MAP 1 (grid 16x16): A-panel XCD ownership. EPI 1: gate epilogue.
template <int EPI, int MAP>
__global__ __launch_bounds__(512, 1) void gemmB(
    const u16* __restrict__ A, const u16* __restrict__ B, int K_loop, int ldk,
    int ldo, void* __restrict__ outp, const float* __restrict__ bias,
    const u16* __restrict__ gate_in) {
  __shared__ char lds[3 * 49152];
  const int tid = threadIdx.x;
  const int w = tid >> 6, l = tid & 63;
  const int wm = w >> 1, wn = w & 1;
  const int fr = l & 15, g = l >> 4;
  int bx, by;
  if (MAP == 1) {
    int b = blockIdx.y * gridDim.x + blockIdx.x;
    int r = b >> 3;
    bx = 2 * (b & 7) + (r >> 4);
    by = r & 15;
  } else {
    int s = blockIdx.y * gridDim.x + blockIdx.x;
    const int nwg = gridDim.x * gridDim.y;
    s = (s & 7) * (nwg >> 3) + (s >> 3);
    bx = s % gridDim.x; by = s / gridDim.x;
  }
  const u16* Ap = A + (size_t)bx * 256 * ldk;
  const u16* Bp = B + (size_t)by * 128 * ldk;
  const int NT = K_loop >> 6;

  f32x4 acc[4][4];
  #pragma unroll
  for (int m = 0; m < 4; ++m)
    #pragma unroll
    for (int n = 0; n < 4; ++n) acc[m][n] = (f32x4){0.f, 0.f, 0.f, 0.f};

  // prologue: tiles 0,1 (6 loads each, FIFO: Bh0 Bh1 Aq0 Aq1 Aq2 Aq3)
  #pragma unroll
  for (int p = 0; p < 2; ++p) {
    char* bA = lds + p * 49152;
    char* bB = bA + 32768;
    const u16* Ak = Ap + (size_t)p * 64;
    const u16* Bk = Bp + (size_t)p * 64;
    stage_rows<1>(Bk, ldk, bB, 0, w, l);
    stage_rows<1>(Bk, ldk, bB, 64, w, l);
    stage_rows<1>(Ak, ldk, bA, 0, w, l);
    stage_rows<1>(Ak, ldk, bA, 64, w, l);
    stage_rows<1>(Ak, ldk, bA, 128, w, l);
    stage_rows<1>(Ak, ldk, bA, 192, w, l);
  }

  int cur = 0;
  for (int t = 0; t < NT; ++t) {
    const bool last = (t == NT - 1);
    const bool dostage = (t + 2 < NT);
    int st = cur + 2; if (st >= 3) st -= 3;
    const char* cbA = lds + cur * 49152;
    const char* cbB = cbA + 32768;
    char* nbA = lds + st * 49152;
    char* nbB = nbA + 32768;
    const u16* An = Ap + (size_t)(t + 2) * 64;
    const u16* Bn = Bp + (size_t)(t + 2) * 64;

    if (last) { asm volatile("s_waitcnt vmcnt(0)" ::: "memory"); }
    else      { asm volatile("s_waitcnt vmcnt(6)" ::: "memory"); }
    __builtin_amdgcn_s_barrier();
    __builtin_amdgcn_sched_barrier(0);

    short8 bf0[4], bf1[4];
    #pragma unroll
    for (int n = 0; n < 4; ++n) {
      bf0[n] = frag8(cbB, wn * 64 + n * 16 + fr, g);
      bf1[n] = frag8(cbB, wn * 64 + n * 16 + fr, 4 + g);
    }
    {  // ph0: m0,m1
      short8 a00 = frag8(cbA, wm * 64 + fr, g);
      short8 a01 = frag8(cbA, wm * 64 + fr, 4 + g);
      short8 a10 = frag8(cbA, wm * 64 + 16 + fr, g);
      short8 a11 = frag8(cbA, wm * 64 + 16 + fr, 4 + g);
      if (dostage) {
        stage_rows<1>(Bn, ldk, nbB, 0, w, l);
        stage_rows<1>(Bn, ldk, nbB, 64, w, l);
        stage_rows<1>(An, ldk, nbA, 0, w, l);
      }
      __builtin_amdgcn_sched_barrier(0);
      __builtin_amdgcn_s_setprio(1);
      #pragma unroll
      for (int n = 0; n < 4; ++n) { MFMA_B16(acc[0][n], a00, bf0[n]); MFMA_B16(acc[1][n], a10, bf0[n]); }
      #pragma unroll
      for (int n = 0; n < 4; ++n) { MFMA_B16(acc[0][n], a01, bf1[n]); MFMA_B16(acc[1][n], a11, bf1[n]); }
      __builtin_amdgcn_s_setprio(0);
    }
    {  // ph1: m2,m3
      short8 a00 = frag8(cbA, wm * 64 + 32 + fr, g);
      short8 a01 = frag8(cbA, wm * 64 + 32 + fr, 4 + g);
      short8 a10 = frag8(cbA, wm * 64 + 48 + fr, g);
      short8 a11 = frag8(cbA, wm * 64 + 48 + fr, 4 + g);
      if (dostage) {
        stage_rows<1>(An, ldk, nbA, 64, w, l);
        stage_rows<1>(An, ldk, nbA, 128, w, l);
        stage_rows<1>(An, ldk, nbA, 192, w, l);
      }
      __builtin_amdgcn_sched_barrier(0);
      __builtin_amdgcn_s_setprio(1);
      #pragma unroll
      for (int n = 0; n < 4; ++n) { MFMA_B16(acc[2][n], a00, bf0[n]); MFMA_B16(acc[3][n], a10, bf0[n]); }
      #pragma unroll
      for (int n = 0; n < 4; ++n) { MFMA_B16(acc[2][n], a01, bf1[n]); MFMA_B16(acc[3][n], a11, bf1[n]); }
      __builtin_amdgcn_s_setprio(0);
    }
    cur = cur + 1; if (cur >= 3) cur = 0;
  }

  const int er = g * 4;
  #pragma unroll
  for (int m = 0; m < 4; ++m)
    #pragma unroll
    for (int n = 0; n < 4; ++n)
      #pragma unroll
      for (int j = 0; j < 4; ++j) {
        int row = bx * 256 + wm * 64 + m * 16 + er + j;
        int col = by * 128 + wn * 64 + n * 16 + fr;
        float v = acc[m][n][j];
        float gt = 1.f / (1.f + __expf(-(v + bias[col])));
        float nv = bf2f(gate_in[(size_t)row * 2048 + col]);
        ((u16*)outp)[(size_t)row * 4096 + 2048 + col] = f2bf(gt * nv);
      }
}

// ========= gemmC: 128x128 tile, BK=64, ring-3 (96KB), unsplit K, fp32 out =========
// Grid 32x8 = 256 blocks (1/CU, zero tail). 8 waves 2Mx4N, wave 64x32,
// acc[4][2]. 4 loads/tile (A:2,B:2); ring-3 counted wait vmcnt(4).
__global__ __launch_bounds__(512, 1) void gemmC(
    const u16* __restrict__ A, const u16* __restrict__ B, int K, int ldk,
    int ldo, float* __restrict__ outp) {
  __shared__ char lds[3 * 32768];
  const int tid = threadIdx.x;
  const int w = tid >> 6, l = tid & 63;
  const int wm = w >> 2, wn = w & 3;
  const int fr = l & 15, g = l >> 4;
  int s = blockIdx.y * gridDim.x + blockIdx.x;
  const int nwg = gridDim.x * gridDim.y;
  s = (s & 7) * (nwg >> 3) + (s >> 3);
  const int bx = s % gridDim.x, by = s / gridDim.x;
  const u16* Ap = A + (size_t)bx * 128 * ldk;
  const u16* Bp = B + (size_t)by * 128 * ldk;
  const int NT = K >> 6;

  f32x4 acc[4][2];
  #pragma unroll
  for (int m = 0; m < 4; ++m)
    #pragma unroll
    for (int n = 0; n < 2; ++n) acc[m][n] = (f32x4){0.f, 0.f, 0.f, 0.f};

  // prologue: tiles 0,1 (FIFO per tile: A(2) then B(2))
  #pragma unroll
  for (int p = 0; p < 2; ++p) {
    char* nb = lds + p * 32768;
    stage_rows<2>(Ap + (size_t)p * 64, ldk, nb, 0, w, l);
    stage_rows<2>(Bp + (size_t)p * 64, ldk, nb + 16384, 0, w, l);
  }

  int cur = 0;
  for (int t = 0; t < NT; ++t) {
    const bool last = (t == NT - 1);
    if (last) { asm volatile("s_waitcnt vmcnt(0)" ::: "memory"); }
    else      { asm volatile("s_waitcnt vmcnt(4)" ::: "memory"); }
    __builtin_amdgcn_s_barrier();
    __builtin_amdgcn_sched_barrier(0);

    const char* cbA = lds + cur * 32768;
    const char* cbB = cbA + 16384;
    short8 af[4][2], bfr[2][2];
    #pragma unroll
    for (int m = 0; m < 4; ++m) {
      af[m][0] = frag8(cbA, wm * 64 + m * 16 + fr, g);
      af[m][1] = frag8(cbA, wm * 64 + m * 16 + fr, 4 + g);
    }
    #pragma unroll
    for (int n = 0; n < 2; ++n) {
      bfr[n][0] = frag8(cbB, wn * 32 + n * 16 + fr, g);
      bfr[n][1] = frag8(cbB, wn * 32 + n * 16 + fr, 4 + g);
    }
    if (t + 2 < NT) {
      int st = cur + 2; if (st >= 3) st -= 3;
      char* nb = lds + st * 32768;
      stage_rows<2>(Ap + (size_t)(t + 2) * 64, ldk, nb, 0, w, l);
      stage_rows<2>(Bp + (size_t)(t + 2) * 64, ldk, nb + 16384, 0, w, l);
    }
    __builtin_amdgcn_sched_barrier(0);
    __builtin_amdgcn_s_setprio(1);
    #pragma unroll
    for (int m = 0; m < 4; ++m)
      #pragma unroll
      for (int n = 0; n < 2; ++n) {
        MFMA_B16(acc[m][n], af[m][0], bfr[n][0]);
        MFMA_B16(acc[m][n], af[m][1], bfr[n][1]);
      }
    __builtin_amdgcn_s_setprio(0);
    cur = cur + 1; if (cur >= 3) cur = 0;
  }

  const int er = g * 4;
  #pragma unroll
  for (int m = 0; m < 4; ++m)
    #pragma unroll
    for (int n = 0; n < 2; ++n)
      #pragma unroll
      for (int j = 0; j < 4; ++j) {
        int row = bx * 128 + wm * 64 + m * 16 + er + j;
        int col = by * 128 + wn * 32 + n * 16 + fr;
        outp[(size_t)row * ldo + col] = acc[m][n][j];
      }
}

// ---------------- fused prep: conv1d+SiLU+split | mlp_skip | dt ----------------
#define NB_CONV 16640   // MROWS*DXBC/2/256
#define NB_MLP  8192    // MROWS*512/256
#define NB_DT   128     // MROWS*8/256

__global__ void prep_kernel(const u16* __restrict__ zx, const float* __restrict__ cw,
                            const float* __restrict__ cb, u16* __restrict__ xc,
                            float* __restrict__ bc, u16* __restrict__ hcat,
                            const float* __restrict__ dt_bias, float* __restrict__ dtb) {
  int blk = blockIdx.x;
  if (blk < NB_CONV) {
    int idx = blk * 256 + threadIdx.x;       // over MROWS * DXBC/2
    int c2 = idx % (DXBC / 2);
    int m = idx / (DXBC / 2);
    int c = c2 * 2;
    int l = m & (SEQLEN - 1);
    const u16* col = zx + (size_t)m * NPAD + 4096 + c;
    float2 cbv = *(const float2*)(cb + c);
    float4 w0 = ((const float4*)cw)[c2 * 2];
    float4 w1 = ((const float4*)cw)[c2 * 2 + 1];
    float a0 = cbv.x, a1 = cbv.y;
    ushort2 t0 = *(const ushort2*)col;
    a0 += w0.w * bf2f(t0.x); a1 += w1.w * bf2f(t0.y);
    if (l >= 1) { ushort2 t = *(const ushort2*)(col - NPAD);     a0 += w0.z * bf2f(t.x); a1 += w1.z * bf2f(t.y); }
    if (l >= 2) { ushort2 t = *(const ushort2*)(col - 2 * NPAD); a0 += w0.y * bf2f(t.x); a1 += w1.y * bf2f(t.y); }
    if (l >= 3) { ushort2 t = *(const ushort2*)(col - 3 * NPAD); a0 += w0.x * bf2f(t.x); a1 += w1.x * bf2f(t.y); }
    float s0 = a0 / (1.f + __expf(-a0));
    float s1 = a1 / (1.f + __expf(-a1));
    if (c < DINNER) {
      ushort2 o; o.x = f2bf(s0); o.y = f2bf(s1);
      *(ushort2*)(xc + (size_t)m * DINNER + c) = o;
    } else {
      float2 o; o.x = s0; o.y = s1;
      *(float2*)(bc + (size_t)m * 32 + (c - DINNER)) = o;
    }
  } else if (blk < NB_CONV + NB_MLP) {
    int i = (blk - NB_CONV) * 256 + threadIdx.x;
    int m = i >> 9, c4 = (i & 511) * 4;
    const u16* row = zx + (size_t)m * NPAD;
    ushort4 zv = *(const ushort4*)(row + c4);
    ushort4 xv = *(const ushort4*)(row + 2048 + c4);
    float z0, x0;
    ushort4 o;
    z0 = bf2f(zv.x); x0 = bf2f(xv.x); o.x = f2bf(x0 * z0 / (1.f + __expf(-z0)));
    z0 = bf2f(zv.y); x0 = bf2f(xv.y); o.y = f2bf(x0 * z0 / (1.f + __expf(-z0)));
    z0 = bf2f(zv.z); x0 = bf2f(xv.z); o.z = f2bf(x0 * z0 / (1.f + __expf(-z0)));
    z0 = bf2f(zv.w); x0 = bf2f(xv.w); o.w = f2bf(x0 * z0 / (1.f + __expf(-z0)));
    *(ushort4*)(hcat + (size_t)m * 4096 + c4) = o;
  } else {
    int idx = (blk - NB_CONV - NB_MLP) * 256 + threadIdx.x;
    if (idx >= MROWS * NHEADS) return;
    int hd = idx & 7, m = idx >> 3;
    float raw = bf2f(zx[(size_t)m * NPAD + 6176 + hd]) + dt_bias[hd];
    float dtv = raw > 20.f ? raw : log1pf(expf(raw));
    dtb[idx] = dtv;
  }
}

// ================= SSD chunked scan =================
__device__ __forceinline__ int xs_addr(int r, int p) {  // byte offset
  return r * 512 + ((((p >> 3) ^ ((r >> 3) & 3)) & 31) << 4) + (p & 7) * 2;
}
__device__ __forceinline__ int P_addr(int t, int s) {   // byte offset, 64x64 bf16
  return t * 128 + ((((s >> 3) ^ (t & 7)) & 7) << 4) + (s & 7) * 2;
}

__device__ __forceinline__ void stage_x(u16* xs, const u16* __restrict__ xc,
                                        size_t base, int tid) {
  #pragma unroll
  for (int it = 0; it < 8; ++it) {
    int r = it * 8 + (tid >> 5);
    int pc = (tid & 31) * 8;
    short8 v = *(const short8*)(xc + base + (size_t)r * DINNER + pc);
    *(short8*)((char*)xs + xs_addr(r, pc)) = v;
  }
}

__device__ __forceinline__ short8 xfrag(const u16* xs, int k0, int g, int p) {
  short8 v;
  #pragma unroll
  for (int j = 0; j < 8; ++j) {
    int s = k0 + g * 8 + j;
    v[j] = *(const short*)((const char*)xs + xs_addr(s, p));
  }
  return v;
}

// S1: per-(bh,chunk) state S_c[n][p] and log-decay prefix lc
__global__ __launch_bounds__(256) void ssd_state(
    const u16* __restrict__ xc, const float* __restrict__ bcb,
    const float* __restrict__ dtb, const float* __restrict__ A_log,
    float* __restrict__ Sbuf, float* __restrict__ lcbuf) {
  __shared__ u16 xs[64 * 256];
  __shared__ float sLC[64], sDT[64];
  __shared__ float wBT[16][65];
  const int tid = threadIdx.x;
  const int bh = blockIdx.x >> 5, c = blockIdx.x & 31;
  const int b = bh >> 3, h = bh & 7;
  const size_t row0 = (size_t)b * SEQLEN + c * CHUNK;
  stage_x(xs, xc, row0 * DINNER + h * HEADDIM, tid);
  if (tid < 64) {
    float dtv = dtb[(row0 + tid) * NHEADS + h];
    float A = -__expf(A_log[h]);
    float s = dtv * A;
    #pragma unroll
    for (int off = 1; off < 64; off <<= 1) {
      float v = __shfl_up(s, off, 64);
      if (tid >= off) s += v;
    }
    sLC[tid] = s; sDT[tid] = dtv;
    lcbuf[(size_t)blockIdx.x * 64 + tid] = s;
  }
  __syncthreads();
  const float lc63 = sLC[63];
  for (int i = tid; i < 1024; i += 256) {
    int n = i & 15, t = i >> 4;
    float w = sDT[t] * __expf(lc63 - sLC[t]);
    wBT[n][t] = w * bcb[(row0 + t) * 32 + n];
  }
  __syncthreads();
  const int lane = tid & 63, w = tid >> 6;
  const int cl = lane & 15, g = lane >> 4;
  f32x4 acc[4];
  #pragma unroll
  for (int pt = 0; pt < 4; ++pt) acc[pt] = (f32x4){0.f, 0.f, 0.f, 0.f};
  #pragma unroll
  for (int kk = 0; kk < 2; ++kk) {
    int k0 = kk * 32;
    short8 af;
    #pragma unroll
    for (int j = 0; j < 8; ++j) af[j] = (short)f2bf(wBT[cl][k0 + g * 8 + j]);
    #pragma unroll
    for (int pt = 0; pt < 4; ++pt) {
      short8 bf = xfrag(xs, k0, g, (w * 4 + pt) * 16 + cl);
      acc[pt] = __builtin_amdgcn_mfma_f32_16x16x32_bf16(af, bf, acc[pt], 0, 0, 0);
    }
  }
  float* Sc = Sbuf + (size_t)blockIdx.x * 16 * 256;
  #pragma unroll
  for (int pt = 0; pt < 4; ++pt)
    #pragma unroll
    for (int j = 0; j < 4; ++j)
      Sc[(g * 4 + j) * 256 + (w * 4 + pt) * 16 + cl] = acc[pt][j];
}

// S2: inter-chunk recurrence, software-pipelined (all 32 loads independent)
__global__ __launch_bounds__(256) void ssd_combine(
    const float* __restrict__ Sbuf, const float* __restrict__ lcbuf,
    float* __restrict__ Sprev) {
  const int bh = blockIdx.x >> 4, seg = blockIdx.x & 15;
  const int idx = seg * 256 + threadIdx.x;   // n*256+p
  float lam[NCHUNK], sv[NCHUNK];
  const size_t base = (size_t)bh * NCHUNK * 4096 + idx;
  #pragma unroll
  for (int c = 0; c < NCHUNK; ++c) {
    lam[c] = lcbuf[((size_t)bh * NCHUNK + c) * 64 + 63];
    sv[c] = Sbuf[base + (size_t)c * 4096];
  }
  #pragma unroll
  for (int c = 0; c < NCHUNK; ++c) lam[c] = __expf(lam[c]);
  float r = 0.f;
  #pragma unroll
  for (int c = 0; c < NCHUNK; ++c) {
    Sprev[base + (size_t)c * 4096] = r;
    r = lam[c] * r + sv[c];
  }
}

// S3: intra-chunk (CB^T masked) @ X + Ce @ Sprev^T + D*x -> y (bf16)
__global__ __launch_bounds__(256) void ssd_out(
    const u16* __restrict__ xc, const float* __restrict__ bcb,
    const float* __restrict__ dtb, const float* __restrict__ lcbuf,
    const float* __restrict__ Sprev, const float* __restrict__ D_par,
    u16* __restrict__ y) {
  __shared__ u16 xs[64 * 256];
  __shared__ u16 P[64 * 64];
  __shared__ u16 sB[64][17], sC[64][17], sCe[64][17];
  __shared__ u16 sSp[256][17];
  __shared__ float sLC[64], sDT[64];
  const int tid = threadIdx.x;
  const int bh = blockIdx.x >> 5, c = blockIdx.x & 31;
  const int b = bh >> 3, h = bh & 7;
  const size_t row0 = (size_t)b * SEQLEN + c * CHUNK;
  stage_x(xs, xc, row0 * DINNER + h * HEADDIM, tid);
  if (tid < 64) {
    sLC[tid] = lcbuf[(size_t)blockIdx.x * 64 + tid];
    sDT[tid] = dtb[(row0 + tid) * NHEADS + h];
  }
  for (int i = tid; i < 1024; i += 256) {
    int n = i & 15, t = i >> 4;
    float Bv = bcb[(row0 + t) * 32 + n];
    float Cv = bcb[(row0 + t) * 32 + 16 + n];
    float e = __expf(lcbuf[(size_t)blockIdx.x * 64 + t]);
    sB[t][n] = f2bf(Bv);
    sC[t][n] = f2bf(Cv);
    sCe[t][n] = f2bf(Cv * e);
  }
  {
    const float* Sp = Sprev + (size_t)blockIdx.x * 4096;
    int p = tid & 255;
    if (tid < 256) {
      #pragma unroll
      for (int n = 0; n < 16; ++n) sSp[p][n] = f2bf(Sp[n * 256 + p]);
    }
  }
  __syncthreads();

  const int lane = tid & 63, w = tid >> 6;
  const int cl = lane & 15, g = lane >> 4;

  f32x4 gacc[4];
  #pragma unroll
  for (int st = 0; st < 4; ++st) gacc[st] = (f32x4){0.f, 0.f, 0.f, 0.f};
  short8 afc = (short8){0, 0, 0, 0, 0, 0, 0, 0};
  if (g < 2) {
    #pragma unroll
    for (int j = 0; j < 8; ++j) afc[j] = (short)sC[w * 16 + cl][g * 8 + j];
  }
  #pragma unroll
  for (int st = 0; st < 4; ++st) {
    short8 bfb = (short8){0, 0, 0, 0, 0, 0, 0, 0};
    if (g < 2) {
      #pragma unroll
      for (int j = 0; j < 8; ++j) bfb[j] = (short)sB[st * 16 + cl][g * 8 + j];
    }
    gacc[st] = __builtin_amdgcn_mfma_f32_16x16x32_bf16(afc, bfb, gacc[st], 0, 0, 0);
  }
  #pragma unroll
  for (int st = 0; st < 4; ++st) {
    #pragma unroll
    for (int j = 0; j < 4; ++j) {
      int t = w * 16 + g * 4 + j;
      int s = st * 16 + cl;
      float v = 0.f;
      if (s <= t) v = gacc[st][j] * sDT[s] * __expf(sLC[t] - sLC[s]);
      *(u16*)((char*)P + P_addr(t, s)) = f2bf(v);
    }
  }
  asm volatile("s_waitcnt lgkmcnt(0)" ::: "memory");
  __builtin_amdgcn_sched_barrier(0);

  f32x4 acc[16];
  #pragma unroll
  for (int pt = 0; pt < 16; ++pt) acc[pt] = (f32x4){0.f, 0.f, 0.f, 0.f};
  #pragma unroll
  for (int kk = 0; kk < 2; ++kk) {
    int k0 = kk * 32;
    short8 ap = *(const short8*)((const char*)P + P_addr(w * 16 + cl, k0 + g * 8));
    #pragma unroll
    for (int pt = 0; pt < 16; ++pt) {
      short8 bf = xfrag(xs, k0, g, pt * 16 + cl);
      acc[pt] = __builtin_amdgcn_mfma_f32_16x16x32_bf16(ap, bf, acc[pt], 0, 0, 0);
    }
  }
  {
    short8 ae = (short8){0, 0, 0, 0, 0, 0, 0, 0};
    if (g < 2) {
      #pragma unroll
      for (int j = 0; j < 8; ++j) ae[j] = (short)sCe[w * 16 + cl][g * 8 + j];
    }
    #pragma unroll
    for (int pt = 0; pt < 16; ++pt) {
      short8 bs = (short8){0, 0, 0, 0, 0, 0, 0, 0};
      if (g < 2) {
        #pragma unroll
        for (int j = 0; j < 8; ++j) bs[j] = (short)sSp[pt * 16 + cl][g * 8 + j];
      }
      acc[pt] = __builtin_amdgcn_mfma_f32_16x16x32_bf16(ae, bs, acc[pt], 0, 0, 0);
    }
  }
  const float Dv = D_par[h];
  #pragma unroll
  for (int pt = 0; pt < 16; ++pt) {
    #pragma unroll
    for (int j = 0; j < 4; ++j) {
      int t = w * 16 + g * 4 + j;
      int p = pt * 16 + cl;
      float xv = bf2f(*(const u16*)((const char*)xs + xs_addr(t, p)));
      float v = acc[pt][j] + Dv * xv;
      y[(row0 + t) * DINNER + h * HEADDIM + p] = f2bf(v);
    }
  }
}

// ---------------- layernorm (bf16 in) -> bf16 ----------------
__global__ __launch_bounds__(256) void ln_kernel(const u16* __restrict__ y,
                                                 const float* __restrict__ gamma,
                                                 const float* __restrict__ beta,
                                                 u16* __restrict__ nrm) {
  const int row = blockIdx.x;
  const int t = threadIdx.x;
  const u16* yr = y + (size_t)row * DINNER;
  short8 v = *(const short8*)(yr + t * 8);
  float f[8];
  float s = 0.f, ss = 0.f;
  #pragma unroll
  for (int j = 0; j < 8; ++j) {
    f[j] = bf2f((u16)v[j]);
    s += f[j]; ss += f[j] * f[j];
  }
  #pragma unroll
  for (int o = 1; o < 64; o <<= 1) { s += __shfl_xor(s, o); ss += __shfl_xor(ss, o); }
  __shared__ float rs[4], rss[4];
  const int wid = t >> 6;
  if ((t & 63) == 0) { rs[wid] = s; rss[wid] = ss; }
  __syncthreads();
  s = rs[0] + rs[1] + rs[2] + rs[3];
  ss = rss[0] + rss[1] + rss[2] + rss[3];
  float mu = s * (1.f / DINNER);
  float var = ss * (1.f / DINNER) - mu * mu;
  float inv = rsqrtf(var + 1e-5f);
  float4 g0 = ((const float4*)gamma)[t * 2], g1 = ((const float4*)gamma)[t * 2 + 1];
  float4 b0 = ((const float4*)beta)[t * 2], b1 = ((const float4*)beta)[t * 2 + 1];
  short8 o;
  o[0] = (short)f2bf((f[0] - mu) * inv * g0.x + b0.x);
  o[1] = (short)f2bf((f[1] - mu) * inv * g0.y + b0.y);
  o[2] = (short)f2bf((f[2] - mu) * inv * g0.z + b0.z);
  o[3] = (short)f2bf((f[3] - mu) * inv * g0.w + b0.w);
  o[4] = (short)f2bf((f[4] - mu) * inv * g1.x + b1.x);
  o[5] = (short)f2bf((f[5] - mu) * inv * g1.y + b1.y);
  o[6] = (short)f2bf((f[6] - mu) * inv * g1.z + b1.z);
  o[7] = (short)f2bf((f[7] - mu) * inv * g1.w + b1.w);
  *(short8*)(nrm + (size_t)row * DINNER + t * 8) = o;
}

// ---------------- host ----------------
extern "C" void kernel_launch(void* const* d_in, const int* in_sizes, int n_in,
                              void* d_out, int out_size, void* d_ws, size_t ws_size,
                              hipStream_t stream) {
  (void)in_sizes; (void)n_in; (void)out_size; (void)ws_size;
  const float* u       = (const float*)d_in[0];
  const float* W_in    = (const float*)d_in[1];
  const float* conv_w  = (const float*)d_in[2];
  const float* conv_b  = (const float*)d_in[3];
  const float* dt_bias = (const float*)d_in[4];
  const float* A_log   = (const float*)d_in[5];
  const float* D_par   = (const float*)d_in[6];
  const float* ln_g    = (const float*)d_in[7];
  const float* ln_b    = (const float*)d_in[8];
  const float* W_gate  = (const float*)d_in[9];
  const float* b_gate  = (const float*)d_in[10];
  const float* W_out   = (const float*)d_in[11];
  float* out = (float*)d_out;

  size_t off = 0;
  auto take = [&](size_t bytes) -> char* {
    char* p = (char*)d_ws + off;
    off = (off + bytes + 255) & ~(size_t)255;
    return p;
  };
  u16* u16b  = (u16*)take((size_t)MROWS * DMODEL * 2);          // dead after gemmA
  u16* Wp    = (u16*)take((size_t)NPAD * DMODEL * 2);           // dead after gemmA
  u16* Wg    = (u16*)take((size_t)DINNER * DINNER * 2);         // dead after gemm1
  u16* Wo    = (u16*)take((size_t)DMODEL * 2 * DINNER * 2);
  u16* zx    = (u16*)take((size_t)MROWS * NPAD * 2);            // 52.4 MB
  u16* xc    = (u16*)take((size_t)MROWS * DINNER * 2);
  float* bcb = (float*)take((size_t)MROWS * 32 * 4);
  float* dtb = (float*)take((size_t)MROWS * NHEADS * 4);
  float* lcbuf = (float*)take((size_t)BH * NCHUNK * 64 * 4);
  u16* nrm   = (u16*)take((size_t)MROWS * DINNER * 2);
  u16* hcat  = (u16*)take((size_t)MROWS * 2 * DINNER * 2);

  float* Sbuf  = (float*)u16b;                                   // 8 MB (u16b dead)
  u16*   y     = zx;                                             // 16 MB
  float* Sprev = (float*)((char*)zx + (size_t)16 * 1024 * 1024); // 8 MB

  cvt_all<<<4096, 256, 0, stream>>>(u, W_gate, W_out, W_in, u16b, Wg, Wo, Wp);

  // gemm0: 256x256 tiles, grid 16x25=400
  gemmA<<<dim3(MROWS / 256, NPAD / 256), 512, 0, stream>>>(
      u16b, Wp, DMODEL, DMODEL, NPAD, zx);

  prep_kernel<<<NB_CONV + NB_MLP + NB_DT, 256, 0, stream>>>(
      zx, conv_w, conv_b, xc, bcb, hcat, dt_bias, dtb);

  ssd_state<<<BH * NCHUNK, 256, 0, stream>>>(xc, bcb, dtb, A_log, Sbuf, lcbuf);
  ssd_combine<<<BH * 16, 256, 0, stream>>>(Sbuf, lcbuf, Sprev);
  ssd_out<<<BH * NCHUNK, 256, 0, stream>>>(xc, bcb, dtb, lcbuf, Sprev, D_par, y);

  ln_kernel<<<MROWS, 256, 0, stream>>>(y, ln_g, ln_b, nrm);

  // gemm1: 256x128 tiles, ring-3, unsplit K, fused gate; grid 16x16 (MAP 1)
  gemmB<1, 1><<<dim3(MROWS / 256, DINNER / 128), 512, 0, stream>>>(
      nrm, Wg, DINNER, DINNER, 0, hcat, b_gate, nrm);

  // gemm2: 128x128 tiles, ring-3, unsplit K=4096, fp32 out; grid 32x8=256
  gemmC<<<dim3(MROWS / 128, DMODEL / 128), 512, 0, stream>>>(
      hcat, Wo, 2 * DINNER, 2 * DINNER, DMODEL, out);
}

// Round 13
// 208.154 us; speedup vs baseline: 1.3004x; 1.1130x over previous
//
#include <hip/hip_runtime.h>
#include <hip/hip_bf16.h>
#include <math.h>

#define BATCH   2
#define SEQLEN  2048
#define DMODEL  1024
#define DINNER  2048
#define DSTATE  16
#define NHEADS  8
#define HEADDIM 256
#define DXBC    2080
#define NPACK   6184   // used cols of in_proj: 0..4095 (z0,x0) + 6144..8231 (xBC,dt)
#define NPAD    6400   // NPACK padded to 256 (for 256-wide GEMM tiles)
#define MROWS   4096   // BATCH*SEQLEN
#define CHUNK   64
#define NCHUNK  32
#define BH      16

typedef unsigned int u32;
typedef unsigned short u16;
typedef __attribute__((ext_vector_type(8))) short short8;
typedef __attribute__((ext_vector_type(4))) float f32x4;

#define GLOAD16(g, l) __builtin_amdgcn_global_load_lds( \
    (const __attribute__((address_space(1))) u32*)(g),  \
    (__attribute__((address_space(3))) u32*)(l), 16, 0, 0)

#define MFMA_B16(d, a, b) d = __builtin_amdgcn_mfma_f32_16x16x32_bf16(a, b, d, 0, 0, 0)

__device__ __forceinline__ u16 f2bf(float f) {
  union { float f; u32 u; } v; v.f = f;
  u32 r = v.u + 0x7fff + ((v.u >> 16) & 1);
  return (u16)(r >> 16);
}
__device__ __forceinline__ float bf2f(u16 b) {
  union { u32 u; float f; } v; v.u = ((u32)b) << 16;
  return v.f;
}

// ---------------- fused conversions ----------------
#define S_U   1048576           // MROWS*DMODEL/4
#define S_WG  1048576           // DINNER*DINNER/4
#define S_WO  1048576           // DMODEL*2*DINNER/4
#define S_WP  1638400           // NPAD*256
#define S_TOT (S_U + S_WG + S_WO + S_WP)

__global__ void cvt_all(const float* __restrict__ u, const float* __restrict__ Wg,
                        const float* __restrict__ Wo, const float* __restrict__ Win,
                        u16* __restrict__ ub, u16* __restrict__ Wgb,
                        u16* __restrict__ Wob, u16* __restrict__ Wp) {
  for (int i = blockIdx.x * 256 + threadIdx.x; i < S_TOT; i += gridDim.x * 256) {
    const float* src; u16* dst; int idx;
    if (i < S_U) { src = u; dst = ub; idx = i; }
    else if (i < S_U + S_WG) { src = Wg; dst = Wgb; idx = i - S_U; }
    else if (i < S_U + S_WG + S_WO) { src = Wo; dst = Wob; idx = i - S_U - S_WG; }
    else {
      int j = i - S_U - S_WG - S_WO;
      int row = j >> 8, c4 = j & 255;
      ushort4 o = make_ushort4(0, 0, 0, 0);
      if (row < NPACK) {
        int orig = row < 4096 ? row : row + 2048;
        float4 v = ((const float4*)(Win + (size_t)orig * DMODEL))[c4];
        o = make_ushort4(f2bf(v.x), f2bf(v.y), f2bf(v.z), f2bf(v.w));
      }
      ((ushort4*)Wp)[j] = o;
      continue;
    }
    float4 v = ((const float4*)src)[idx];
    ((ushort4*)dst)[idx] = make_ushort4(f2bf(v.x), f2bf(v.y), f2bf(v.z), f2bf(v.w));
  }
}

// ===================== shared GEMM building blocks =====================
template <int NL>
__device__ __forceinline__ void stage_rows(const u16* __restrict__ gsrc, int ldk,
                                           char* ldsmat, int row0, int w, int l) {
  const int rl = w * 8 + (l >> 3);
  const int q = ((l & 7) ^ (l >> 3)) * 8;   // logical element offset for phys slot
  #pragma unroll
  for (int j = 0; j < NL; ++j) {
    GLOAD16(gsrc + (size_t)(row0 + j * 64 + rl) * ldk + q,
            ldsmat + (row0 + j * 64 + w * 8) * 128);
  }
}

__device__ __forceinline__ short8 frag8(const char* mat, int row, int q) {
  return *(const short8*)(mat + row * 128 + ((q ^ (row & 7)) << 4));
}

// ============== gemmA: 256x256 tile, BK=64, 2-buffer, 4-phase ==============
__global__ __launch_bounds__(512, 1) void gemmA(
    const u16* __restrict__ A, const u16* __restrict__ B, int K, int ldk,
    int ldo, u16* __restrict__ outp) {
  __shared__ char lds[131072];
  const int tid = threadIdx.x;
  const int w = tid >> 6, l = tid & 63;
  const int wm = w >> 2, wn = w & 3;
  const int fr = l & 15, g = l >> 4;
  int s = blockIdx.y * gridDim.x + blockIdx.x;
  const int nwg = gridDim.x * gridDim.y;
  s = (s & 7) * (nwg >> 3) + (s >> 3);
  const int bx = s % gridDim.x, by = s / gridDim.x;
  const u16* Ap = A + (size_t)bx * 256 * ldk;
  const u16* Bp = B + (size_t)by * 256 * ldk;
  const int NT = K >> 6;

  f32x4 acc[8][4];
  #pragma unroll
  for (int m = 0; m < 8; ++m)
    #pragma unroll
    for (int n = 0; n < 4; ++n) acc[m][n] = (f32x4){0.f, 0.f, 0.f, 0.f};

  // prologue: tile 0 into buf0, FIFO order [Bh0][Bh1][Aq0][Aq2][Aq1][Aq3]
  stage_rows<2>(Bp, ldk, lds + 32768, 0, w, l);
  stage_rows<2>(Bp, ldk, lds + 32768, 128, w, l);
  stage_rows<1>(Ap, ldk, lds, 0, w, l);
  stage_rows<1>(Ap, ldk, lds, 128, w, l);
  stage_rows<1>(Ap, ldk, lds, 64, w, l);
  stage_rows<1>(Ap, ldk, lds, 192, w, l);

  for (int t = 0; t < NT; ++t) {
    const bool last = (t == NT - 1);
    const char* cbA = lds + (t & 1) * 65536;
    const char* cbB = cbA + 32768;
    char* nbA = lds + ((t + 1) & 1) * 65536;
    char* nbB = nbA + 32768;
    const u16* An = Ap + (size_t)(t + 1) * 64;
    const u16* Bn = Bp + (size_t)(t + 1) * 64;

    asm volatile("s_waitcnt vmcnt(2)" ::: "memory");
    __builtin_amdgcn_s_barrier();
    __builtin_amdgcn_sched_barrier(0);

    short8 bf0[4], bf1[4];
    #pragma unroll
    for (int n = 0; n < 4; ++n) {
      bf0[n] = frag8(cbB, wn * 64 + n * 16 + fr, g);
      bf1[n] = frag8(cbB, wn * 64 + n * 16 + fr, 4 + g);
    }
    {  // ph0: m0,m1
      short8 a00 = frag8(cbA, wm * 128 + fr, g);
      short8 a01 = frag8(cbA, wm * 128 + fr, 4 + g);
      short8 a10 = frag8(cbA, wm * 128 + 16 + fr, g);
      short8 a11 = frag8(cbA, wm * 128 + 16 + fr, 4 + g);
      if (!last) stage_rows<2>(Bn, ldk, nbB, 0, w, l);
      __builtin_amdgcn_sched_barrier(0);
      __builtin_amdgcn_s_setprio(1);
      #pragma unroll
      for (int n = 0; n < 4; ++n) { MFMA_B16(acc[0][n], a00, bf0[n]); MFMA_B16(acc[1][n], a10, bf0[n]); }
      #pragma unroll
      for (int n = 0; n < 4; ++n) { MFMA_B16(acc[0][n], a01, bf1[n]); MFMA_B16(acc[1][n], a11, bf1[n]); }
      __builtin_amdgcn_s_setprio(0);
    }
    {  // ph1: m2,m3
      short8 a00 = frag8(cbA, wm * 128 + 32 + fr, g);
      short8 a01 = frag8(cbA, wm * 128 + 32 + fr, 4 + g);
      short8 a10 = frag8(cbA, wm * 128 + 48 + fr, g);
      short8 a11 = frag8(cbA, wm * 128 + 48 + fr, 4 + g);
      if (!last) stage_rows<2>(Bn, ldk, nbB, 128, w, l);
      __builtin_amdgcn_sched_barrier(0);
      __builtin_amdgcn_s_setprio(1);
      #pragma unroll
      for (int n = 0; n < 4; ++n) { MFMA_B16(acc[2][n], a00, bf0[n]); MFMA_B16(acc[3][n], a10, bf0[n]); }
      #pragma unroll
      for (int n = 0; n < 4; ++n) { MFMA_B16(acc[2][n], a01, bf1[n]); MFMA_B16(acc[3][n], a11, bf1[n]); }
      __builtin_amdgcn_s_setprio(0);
    }
    if (last) { asm volatile("s_waitcnt vmcnt(0)" ::: "memory"); }
    else      { asm volatile("s_waitcnt vmcnt(4)" ::: "memory"); }
    __builtin_amdgcn_s_barrier();
    __builtin_amdgcn_sched_barrier(0);
    {  // ph2: m4,m5
      short8 a00 = frag8(cbA, wm * 128 + 64 + fr, g);
      short8 a01 = frag8(cbA, wm * 128 + 64 + fr, 4 + g);
      short8 a10 = frag8(cbA, wm * 128 + 80 + fr, g);
      short8 a11 = frag8(cbA, wm * 128 + 80 + fr, 4 + g);
      if (!last) { stage_rows<1>(An, ldk, nbA, 0, w, l); stage_rows<1>(An, ldk, nbA, 128, w, l); }
      __builtin_amdgcn_sched_barrier(0);
      __builtin_amdgcn_s_setprio(1);
      #pragma unroll
      for (int n = 0; n < 4; ++n) { MFMA_B16(acc[4][n], a00, bf0[n]); MFMA_B16(acc[5][n], a10, bf0[n]); }
      #pragma unroll
      for (int n = 0; n < 4; ++n) { MFMA_B16(acc[4][n], a01, bf1[n]); MFMA_B16(acc[5][n], a11, bf1[n]); }
      __builtin_amdgcn_s_setprio(0);
    }
    {  // ph3: m6,m7
      short8 a00 = frag8(cbA, wm * 128 + 96 + fr, g);
      short8 a01 = frag8(cbA, wm * 128 + 96 + fr, 4 + g);
      short8 a10 = frag8(cbA, wm * 128 + 112 + fr, g);
      short8 a11 = frag8(cbA, wm * 128 + 112 + fr, 4 + g);
      if (!last) { stage_rows<1>(An, ldk, nbA, 64, w, l); stage_rows<1>(An, ldk, nbA, 192, w, l); }
      __builtin_amdgcn_sched_barrier(0);
      __builtin_amdgcn_s_setprio(1);
      #pragma unroll
      for (int n = 0; n < 4; ++n) { MFMA_B16(acc[6][n], a00, bf0[n]); MFMA_B16(acc[7][n], a10, bf0[n]); }
      #pragma unroll
      for (int n = 0; n < 4; ++n) { MFMA_B16(acc[6][n], a01, bf1[n]); MFMA_B16(acc[7][n], a11, bf1[n]); }
      __builtin_amdgcn_s_setprio(0);
    }
  }

  const int er = g * 4;
  #pragma unroll
  for (int m = 0; m < 8; ++m)
    #pragma unroll
    for (int n = 0; n < 4; ++n)
      #pragma unroll
      for (int j = 0; j < 4; ++j) {
        int row = bx * 256 + wm * 128 + m * 16 + er + j;
        int col = by * 256 + wn * 64 + n * 16 + fr;
        outp[(size_t)row * ldo + col] = f2bf(acc[m][n][j]);
      }
}

// ============== gemmB: 256x128 tile, BK=64, ring-3, 2-phase ==============
// MAP 1 (grid 16x16): A-panel XCD ownership. EPI 1: gate epilogue.
template <int EPI, int MAP>
__global__ __launch_bounds__(512, 1) void gemmB(
    const u16* __restrict__ A, const u16* __restrict__ B, int K_loop, int ldk,
    int ldo, void* __restrict__ outp, const float* __restrict__ bias,
    const u16* __restrict__ gate_in) {
  __shared__ char lds[3 * 49152];
  const int tid = threadIdx.x;
  const int w = tid >> 6, l = tid & 63;
  const int wm = w >> 1, wn = w & 1;
  const int fr = l & 15, g = l >> 4;
  int bx, by;
  if (MAP == 1) {
    int b = blockIdx.y * gridDim.x + blockIdx.x;
    int r = b >> 3;
    bx = 2 * (b & 7) + (r >> 4);
    by = r & 15;
  } else {
    int s = blockIdx.y * gridDim.x + blockIdx.x;
    const int nwg = gridDim.x * gridDim.y;
    s = (s & 7) * (nwg >> 3) + (s >> 3);
    bx = s % gridDim.x; by = s / gridDim.x;
  }
  const u16* Ap = A + (size_t)bx * 256 * ldk;
  const u16* Bp = B + (size_t)by * 128 * ldk;
  const int NT = K_loop >> 6;

  f32x4 acc[4][4];
  #pragma unroll
  for (int m = 0; m < 4; ++m)
    #pragma unroll
    for (int n = 0; n < 4; ++n) acc[m][n] = (f32x4){0.f, 0.f, 0.f, 0.f};

  // prologue: tiles 0,1 (6 loads each, FIFO: Bh0 Bh1 Aq0 Aq1 Aq2 Aq3)
  #pragma unroll
  for (int p = 0; p < 2; ++p) {
    char* bA = lds + p * 49152;
    char* bB = bA + 32768;
    const u16* Ak = Ap + (size_t)p * 64;
    const u16* Bk = Bp + (size_t)p * 64;
    stage_rows<1>(Bk, ldk, bB, 0, w, l);
    stage_rows<1>(Bk, ldk, bB, 64, w, l);
    stage_rows<1>(Ak, ldk, bA, 0, w, l);
    stage_rows<1>(Ak, ldk, bA, 64, w, l);
    stage_rows<1>(Ak, ldk, bA, 128, w, l);
    stage_rows<1>(Ak, ldk, bA, 192, w, l);
  }

  int cur = 0;
  for (int t = 0; t < NT; ++t) {
    const bool last = (t == NT - 1);
    const bool dostage = (t + 2 < NT);
    int st = cur + 2; if (st >= 3) st -= 3;
    const char* cbA = lds + cur * 49152;
    const char* cbB = cbA + 32768;
    char* nbA = lds + st * 49152;
    char* nbB = nbA + 32768;
    const u16* An = Ap + (size_t)(t + 2) * 64;
    const u16* Bn = Bp + (size_t)(t + 2) * 64;

    if (last) { asm volatile("s_waitcnt vmcnt(0)" ::: "memory"); }
    else      { asm volatile("s_waitcnt vmcnt(6)" ::: "memory"); }
    __builtin_amdgcn_s_barrier();
    __builtin_amdgcn_sched_barrier(0);

    short8 bf0[4], bf1[4];
    #pragma unroll
    for (int n = 0; n < 4; ++n) {
      bf0[n] = frag8(cbB, wn * 64 + n * 16 + fr, g);
      bf1[n] = frag8(cbB, wn * 64 + n * 16 + fr, 4 + g);
    }
    {  // ph0: m0,m1
      short8 a00 = frag8(cbA, wm * 64 + fr, g);
      short8 a01 = frag8(cbA, wm * 64 + fr, 4 + g);
      short8 a10 = frag8(cbA, wm * 64 + 16 + fr, g);
      short8 a11 = frag8(cbA, wm * 64 + 16 + fr, 4 + g);
      if (dostage) {
        stage_rows<1>(Bn, ldk, nbB, 0, w, l);
        stage_rows<1>(Bn, ldk, nbB, 64, w, l);
        stage_rows<1>(An, ldk, nbA, 0, w, l);
      }
      __builtin_amdgcn_sched_barrier(0);
      __builtin_amdgcn_s_setprio(1);
      #pragma unroll
      for (int n = 0; n < 4; ++n) { MFMA_B16(acc[0][n], a00, bf0[n]); MFMA_B16(acc[1][n], a10, bf0[n]); }
      #pragma unroll
      for (int n = 0; n < 4; ++n) { MFMA_B16(acc[0][n], a01, bf1[n]); MFMA_B16(acc[1][n], a11, bf1[n]); }
      __builtin_amdgcn_s_setprio(0);
    }
    {  // ph1: m2,m3
      short8 a00 = frag8(cbA, wm * 64 + 32 + fr, g);
      short8 a01 = frag8(cbA, wm * 64 + 32 + fr, 4 + g);
      short8 a10 = frag8(cbA, wm * 64 + 48 + fr, g);
      short8 a11 = frag8(cbA, wm * 64 + 48 + fr, 4 + g);
      if (dostage) {
        stage_rows<1>(An, ldk, nbA, 64, w, l);
        stage_rows<1>(An, ldk, nbA, 128, w, l);
        stage_rows<1>(An, ldk, nbA, 192, w, l);
      }
      __builtin_amdgcn_sched_barrier(0);
      __builtin_amdgcn_s_setprio(1);
      #pragma unroll
      for (int n = 0; n < 4; ++n) { MFMA_B16(acc[2][n], a00, bf0[n]); MFMA_B16(acc[3][n], a10, bf0[n]); }
      #pragma unroll
      for (int n = 0; n < 4; ++n) { MFMA_B16(acc[2][n], a01, bf1[n]); MFMA_B16(acc[3][n], a11, bf1[n]); }
      __builtin_amdgcn_s_setprio(0);
    }
    cur = cur + 1; if (cur >= 3) cur = 0;
  }

  const int er = g * 4;
  #pragma unroll
  for (int m = 0; m < 4; ++m)
    #pragma unroll
    for (int n = 0; n < 4; ++n)
      #pragma unroll
      for (int j = 0; j < 4; ++j) {
        int row = bx * 256 + wm * 64 + m * 16 + er + j;
        int col = by * 128 + wn * 64 + n * 16 + fr;
        float v = acc[m][n][j];
        float gt = 1.f / (1.f + __expf(-(v + bias[col])));
        float nv = bf2f(gate_in[(size_t)row * 2048 + col]);
        ((u16*)outp)[(size_t)row * 4096 + 2048 + col] = f2bf(gt * nv);
      }
}

// ========= gemmC: 128x128 tile, BK=64, ring-3 (96KB), unsplit K, fp32 out =========
__global__ __launch_bounds__(512, 1) void gemmC(
    const u16* __restrict__ A, const u16* __restrict__ B, int K, int ldk,
    int ldo, float* __restrict__ outp) {
  __shared__ char lds[3 * 32768];
  const int tid = threadIdx.x;
  const int w = tid >> 6, l = tid & 63;
  const int wm = w >> 2, wn = w & 3;
  const int fr = l & 15, g = l >> 4;
  int s = blockIdx.y * gridDim.x + blockIdx.x;
  const int nwg = gridDim.x * gridDim.y;
  s = (s & 7) * (nwg >> 3) + (s >> 3);
  const int bx = s % gridDim.x, by = s / gridDim.x;
  const u16* Ap = A + (size_t)bx * 128 * ldk;
  const u16* Bp = B + (size_t)by * 128 * ldk;
  const int NT = K >> 6;

  f32x4 acc[4][2];
  #pragma unroll
  for (int m = 0; m < 4; ++m)
    #pragma unroll
    for (int n = 0; n < 2; ++n) acc[m][n] = (f32x4){0.f, 0.f, 0.f, 0.f};

  // prologue: tiles 0,1 (FIFO per tile: A(2) then B(2))
  #pragma unroll
  for (int p = 0; p < 2; ++p) {
    char* nb = lds + p * 32768;
    stage_rows<2>(Ap + (size_t)p * 64, ldk, nb, 0, w, l);
    stage_rows<2>(Bp + (size_t)p * 64, ldk, nb + 16384, 0, w, l);
  }

  int cur = 0;
  for (int t = 0; t < NT; ++t) {
    const bool last = (t == NT - 1);
    if (last) { asm volatile("s_waitcnt vmcnt(0)" ::: "memory"); }
    else      { asm volatile("s_waitcnt vmcnt(4)" ::: "memory"); }
    __builtin_amdgcn_s_barrier();
    __builtin_amdgcn_sched_barrier(0);

    const char* cbA = lds + cur * 32768;
    const char* cbB = cbA + 16384;
    short8 af[4][2], bfr[2][2];
    #pragma unroll
    for (int m = 0; m < 4; ++m) {
      af[m][0] = frag8(cbA, wm * 64 + m * 16 + fr, g);
      af[m][1] = frag8(cbA, wm * 64 + m * 16 + fr, 4 + g);
    }
    #pragma unroll
    for (int n = 0; n < 2; ++n) {
      bfr[n][0] = frag8(cbB, wn * 32 + n * 16 + fr, g);
      bfr[n][1] = frag8(cbB, wn * 32 + n * 16 + fr, 4 + g);
    }
    if (t + 2 < NT) {
      int st = cur + 2; if (st >= 3) st -= 3;
      char* nb = lds + st * 32768;
      stage_rows<2>(Ap + (size_t)(t + 2) * 64, ldk, nb, 0, w, l);
      stage_rows<2>(Bp + (size_t)(t + 2) * 64, ldk, nb + 16384, 0, w, l);
    }
    __builtin_amdgcn_sched_barrier(0);
    __builtin_amdgcn_s_setprio(1);
    #pragma unroll
    for (int m = 0; m < 4; ++m)
      #pragma unroll
      for (int n = 0; n < 2; ++n) {
        MFMA_B16(acc[m][n], af[m][0], bfr[n][0]);
        MFMA_B16(acc[m][n], af[m][1], bfr[n][1]);
      }
    __builtin_amdgcn_s_setprio(0);
    cur = cur + 1; if (cur >= 3) cur = 0;
  }

  const int er = g * 4;
  #pragma unroll
  for (int m = 0; m < 4; ++m)
    #pragma unroll
    for (int n = 0; n < 2; ++n)
      #pragma unroll
      for (int j = 0; j < 4; ++j) {
        int row = bx * 128 + wm * 64 + m * 16 + er + j;
        int col = by * 128 + wn * 32 + n * 16 + fr;
        outp[(size_t)row * ldo + col] = acc[m][n][j];
      }
}

// ---------------- fused prep: conv1d(4-step/thread)+SiLU+split | mlp_skip | dt ----------------
#define NB_CONV 4160    // (MROWS/4)*(DXBC/2)/256
#define NB_MLP  8192    // MROWS*512/256
#define NB_DT   128     // MROWS*8/256

__global__ void prep_kernel(const u16* __restrict__ zx, const float* __restrict__ cw,
                            const float* __restrict__ cb, u16* __restrict__ xc,
                            float* __restrict__ bc, u16* __restrict__ hcat,
                            const float* __restrict__ dt_bias, float* __restrict__ dtb) {
  int blk = blockIdx.x;
  if (blk < NB_CONV) {
    int idx = blk * 256 + threadIdx.x;       // over (MROWS/4) * (DXBC/2)
    int c2 = idx % (DXBC / 2);
    int mg = idx / (DXBC / 2);
    int c = c2 * 2;
    int m0 = mg * 4;
    int l0 = m0 & (SEQLEN - 1);
    const u16* col = zx + (size_t)m0 * NPAD + 4096 + c;
    float2 cbv = *(const float2*)(cb + c);
    float4 w0 = ((const float4*)cw)[c2 * 2];      // weights for col c   (w[0..3])
    float4 w1 = ((const float4*)cw)[c2 * 2 + 1];  // weights for col c+1
    // window rows m0-3 .. m0+3 ; r[j] = row m0-3+j
    ushort2 r[7];
    #pragma unroll
    for (int i = 0; i < 4; ++i) r[3 + i] = *(const ushort2*)(col + (size_t)i * NPAD);
    r[2] = l0 >= 1 ? *(const ushort2*)(col - NPAD)     : make_ushort2(0, 0);
    r[1] = l0 >= 2 ? *(const ushort2*)(col - 2 * NPAD) : make_ushort2(0, 0);
    r[0] = l0 >= 3 ? *(const ushort2*)(col - 3 * NPAD) : make_ushort2(0, 0);
    #pragma unroll
    for (int i = 0; i < 4; ++i) {
      int l = l0 + i;
      float a0 = cbv.x + w0.w * bf2f(r[3 + i].x);
      float a1 = cbv.y + w1.w * bf2f(r[3 + i].y);
      if (l >= 1) { a0 += w0.z * bf2f(r[2 + i].x); a1 += w1.z * bf2f(r[2 + i].y); }
      if (l >= 2) { a0 += w0.y * bf2f(r[1 + i].x); a1 += w1.y * bf2f(r[1 + i].y); }
      if (l >= 3) { a0 += w0.x * bf2f(r[i].x);     a1 += w1.x * bf2f(r[i].y); }
      float s0 = a0 / (1.f + __expf(-a0));
      float s1 = a1 / (1.f + __expf(-a1));
      int m = m0 + i;
      if (c < DINNER) {
        ushort2 o; o.x = f2bf(s0); o.y = f2bf(s1);
        *(ushort2*)(xc + (size_t)m * DINNER + c) = o;
      } else {
        float2 o; o.x = s0; o.y = s1;
        *(float2*)(bc + (size_t)m * 32 + (c - DINNER)) = o;
      }
    }
  } else if (blk < NB_CONV + NB_MLP) {
    int i = (blk - NB_CONV) * 256 + threadIdx.x;
    int m = i >> 9, c4 = (i & 511) * 4;
    const u16* row = zx + (size_t)m * NPAD;
    ushort4 zv = *(const ushort4*)(row + c4);
    ushort4 xv = *(const ushort4*)(row + 2048 + c4);
    float z0, x0;
    ushort4 o;
    z0 = bf2f(zv.x); x0 = bf2f(xv.x); o.x = f2bf(x0 * z0 / (1.f + __expf(-z0)));
    z0 = bf2f(zv.y); x0 = bf2f(xv.y); o.y = f2bf(x0 * z0 / (1.f + __expf(-z0)));
    z0 = bf2f(zv.z); x0 = bf2f(xv.z); o.z = f2bf(x0 * z0 / (1.f + __expf(-z0)));
    z0 = bf2f(zv.w); x0 = bf2f(xv.w); o.w = f2bf(x0 * z0 / (1.f + __expf(-z0)));
    *(ushort4*)(hcat + (size_t)m * 4096 + c4) = o;
  } else {
    int idx = (blk - NB_CONV - NB_MLP) * 256 + threadIdx.x;
    if (idx >= MROWS * NHEADS) return;
    int hd = idx & 7, m = idx >> 3;
    float raw = bf2f(zx[(size_t)m * NPAD + 6176 + hd]) + dt_bias[hd];
    float dtv = raw > 20.f ? raw : log1pf(expf(raw));
    dtb[idx] = dtv;
  }
}

// ================= SSD chunked scan =================
__device__ __forceinline__ int xs_addr(int r, int p) {  // byte offset
  return r * 512 + ((((p >> 3) ^ ((r >> 3) & 3)) & 31) << 4) + (p & 7) * 2;
}
__device__ __forceinline__ int P_addr(int t, int s) {   // byte offset, 64x64 bf16
  return t * 128 + ((((s >> 3) ^ (t & 7)) & 7) << 4) + (s & 7) * 2;
}

__device__ __forceinline__ void stage_x(u16* xs, const u16* __restrict__ xc,
                                        size_t base, int tid) {
  #pragma unroll
  for (int it = 0; it < 8; ++it) {
    int r = it * 8 + (tid >> 5);
    int pc = (tid & 31) * 8;
    short8 v = *(const short8*)(xc + base + (size_t)r * DINNER + pc);
    *(short8*)((char*)xs + xs_addr(r, pc)) = v;
  }
}

__device__ __forceinline__ short8 xfrag(const u16* xs, int k0, int g, int p) {
  short8 v;
  #pragma unroll
  for (int j = 0; j < 8; ++j) {
    int s = k0 + g * 8 + j;
    v[j] = *(const short*)((const char*)xs + xs_addr(s, p));
  }
  return v;
}

// S1: per-(bh,chunk) state S_c[n][p] and log-decay prefix lc
__global__ __launch_bounds__(256) void ssd_state(
    const u16* __restrict__ xc, const float* __restrict__ bcb,
    const float* __restrict__ dtb, const float* __restrict__ A_log,
    float* __restrict__ Sbuf, float* __restrict__ lcbuf) {
  __shared__ u16 xs[64 * 256];
  __shared__ float sLC[64], sDT[64];
  __shared__ float wBT[16][65];
  const int tid = threadIdx.x;
  const int bh = blockIdx.x >> 5, c = blockIdx.x & 31;
  const int b = bh >> 3, h = bh & 7;
  const size_t row0 = (size_t)b * SEQLEN + c * CHUNK;
  stage_x(xs, xc, row0 * DINNER + h * HEADDIM, tid);
  if (tid < 64) {
    float dtv = dtb[(row0 + tid) * NHEADS + h];
    float A = -__expf(A_log[h]);
    float s = dtv * A;
    #pragma unroll
    for (int off = 1; off < 64; off <<= 1) {
      float v = __shfl_up(s, off, 64);
      if (tid >= off) s += v;
    }
    sLC[tid] = s; sDT[tid] = dtv;
    lcbuf[(size_t)blockIdx.x * 64 + tid] = s;
  }
  __syncthreads();
  const float lc63 = sLC[63];
  for (int i = tid; i < 1024; i += 256) {
    int n = i & 15, t = i >> 4;
    float w = sDT[t] * __expf(lc63 - sLC[t]);
    wBT[n][t] = w * bcb[(row0 + t) * 32 + n];
  }
  __syncthreads();
  const int lane = tid & 63, w = tid >> 6;
  const int cl = lane & 15, g = lane >> 4;
  f32x4 acc[4];
  #pragma unroll
  for (int pt = 0; pt < 4; ++pt) acc[pt] = (f32x4){0.f, 0.f, 0.f, 0.f};
  #pragma unroll
  for (int kk = 0; kk < 2; ++kk) {
    int k0 = kk * 32;
    short8 af;
    #pragma unroll
    for (int j = 0; j < 8; ++j) af[j] = (short)f2bf(wBT[cl][k0 + g * 8 + j]);
    #pragma unroll
    for (int pt = 0; pt < 4; ++pt) {
      short8 bf = xfrag(xs, k0, g, (w * 4 + pt) * 16 + cl);
      acc[pt] = __builtin_amdgcn_mfma_f32_16x16x32_bf16(af, bf, acc[pt], 0, 0, 0);
    }
  }
  float* Sc = Sbuf + (size_t)blockIdx.x * 16 * 256;
  #pragma unroll
  for (int pt = 0; pt < 4; ++pt)
    #pragma unroll
    for (int j = 0; j < 4; ++j)
      Sc[(g * 4 + j) * 256 + (w * 4 + pt) * 16 + cl] = acc[pt][j];
}

// S2: inter-chunk recurrence, software-pipelined (all 32 loads independent)
__global__ __launch_bounds__(256) void ssd_combine(
    const float* __restrict__ Sbuf, const float* __restrict__ lcbuf,
    float* __restrict__ Sprev) {
  const int bh = blockIdx.x >> 4, seg = blockIdx.x & 15;
  const int idx = seg * 256 + threadIdx.x;   // n*256+p
  float lam[NCHUNK], sv[NCHUNK];
  const size_t base = (size_t)bh * NCHUNK * 4096 + idx;
  #pragma unroll
  for (int c = 0; c < NCHUNK; ++c) {
    lam[c] = lcbuf[((size_t)bh * NCHUNK + c) * 64 + 63];
    sv[c] = Sbuf[base + (size_t)c * 4096];
  }
  #pragma unroll
  for (int c = 0; c < NCHUNK; ++c) lam[c] = __expf(lam[c]);
  float r = 0.f;
  #pragma unroll
  for (int c = 0; c < NCHUNK; ++c) {
    Sprev[base + (size_t)c * 4096] = r;
    r = lam[c] * r + sv[c];
  }
}

// S3: intra-chunk (CB^T masked) @ X + Ce @ Sprev^T + D*x -> y (bf16)
__global__ __launch_bounds__(256) void ssd_out(
    const u16* __restrict__ xc, const float* __restrict__ bcb,
    const float* __restrict__ dtb, const float* __restrict__ lcbuf,
    const float* __restrict__ Sprev, const float* __restrict__ D_par,
    u16* __restrict__ y) {
  __shared__ u16 xs[64 * 256];
  __shared__ u16 P[64 * 64];
  __shared__ u16 sB[64][17], sC[64][17], sCe[64][17];
  __shared__ u16 sSp[256][17];
  __shared__ float sLC[64], sDT[64];
  const int tid = threadIdx.x;
  const int bh = blockIdx.x >> 5, c = blockIdx.x & 31;
  const int b = bh >> 3, h = bh & 7;
  const size_t row0 = (size_t)b * SEQLEN + c * CHUNK;
  stage_x(xs, xc, row0 * DINNER + h * HEADDIM, tid);
  if (tid < 64) {
    sLC[tid] = lcbuf[(size_t)blockIdx.x * 64 + tid];
    sDT[tid] = dtb[(row0 + tid) * NHEADS + h];
  }
  for (int i = tid; i < 1024; i += 256) {
    int n = i & 15, t = i >> 4;
    float Bv = bcb[(row0 + t) * 32 + n];
    float Cv = bcb[(row0 + t) * 32 + 16 + n];
    float e = __expf(lcbuf[(size_t)blockIdx.x * 64 + t]);
    sB[t][n] = f2bf(Bv);
    sC[t][n] = f2bf(Cv);
    sCe[t][n] = f2bf(Cv * e);
  }
  {
    const float* Sp = Sprev + (size_t)blockIdx.x * 4096;
    int p = tid & 255;
    if (tid < 256) {
      #pragma unroll
      for (int n = 0; n < 16; ++n) sSp[p][n] = f2bf(Sp[n * 256 + p]);
    }
  }
  __syncthreads();

  const int lane = tid & 63, w = tid >> 6;
  const int cl = lane & 15, g = lane >> 4;

  f32x4 gacc[4];
  #pragma unroll
  for (int st = 0; st < 4; ++st) gacc[st] = (f32x4){0.f, 0.f, 0.f, 0.f};
  short8 afc = (short8){0, 0, 0, 0, 0, 0, 0, 0};
  if (g < 2) {
    #pragma unroll
    for (int j = 0; j < 8; ++j) afc[j] = (short)sC[w * 16 + cl][g * 8 + j];
  }
  #pragma unroll
  for (int st = 0; st < 4; ++st) {
    short8 bfb = (short8){0, 0, 0, 0, 0, 0, 0, 0};
    if (g < 2) {
      #pragma unroll
      for (int j = 0; j < 8; ++j) bfb[j] = (short)sB[st * 16 + cl][g * 8 + j];
    }
    gacc[st] = __builtin_amdgcn_mfma_f32_16x16x32_bf16(afc, bfb, gacc[st], 0, 0, 0);
  }
  #pragma unroll
  for (int st = 0; st < 4; ++st) {
    #pragma unroll
    for (int j = 0; j < 4; ++j) {
      int t = w * 16 + g * 4 + j;
      int s = st * 16 + cl;
      float v = 0.f;
      if (s <= t) v = gacc[st][j] * sDT[s] * __expf(sLC[t] - sLC[s]);
      *(u16*)((char*)P + P_addr(t, s)) = f2bf(v);
    }
  }
  asm volatile("s_waitcnt lgkmcnt(0)" ::: "memory");
  __builtin_amdgcn_sched_barrier(0);

  f32x4 acc[16];
  #pragma unroll
  for (int pt = 0; pt < 16; ++pt) acc[pt] = (f32x4){0.f, 0.f, 0.f, 0.f};
  #pragma unroll
  for (int kk = 0; kk < 2; ++kk) {
    int k0 = kk * 32;
    short8 ap = *(const short8*)((const char*)P + P_addr(w * 16 + cl, k0 + g * 8));
    #pragma unroll
    for (int pt = 0; pt < 16; ++pt) {
      short8 bf = xfrag(xs, k0, g, pt * 16 + cl);
      acc[pt] = __builtin_amdgcn_mfma_f32_16x16x32_bf16(ap, bf, acc[pt], 0, 0, 0);
    }
  }
  {
    short8 ae = (short8){0, 0, 0, 0, 0, 0, 0, 0};
    if (g < 2) {
      #pragma unroll
      for (int j = 0; j < 8; ++j) ae[j] = (short)sCe[w * 16 + cl][g * 8 + j];
    }
    #pragma unroll
    for (int pt = 0; pt < 16; ++pt) {
      short8 bs = (short8){0, 0, 0, 0, 0, 0, 0, 0};
      if (g < 2) {
        #pragma unroll
        for (int j = 0; j < 8; ++j) bs[j] = (short)sSp[pt * 16 + cl][g * 8 + j];
      }
      acc[pt] = __builtin_amdgcn_mfma_f32_16x16x32_bf16(ae, bs, acc[pt], 0, 0, 0);
    }
  }
  const float Dv = D_par[h];
  #pragma unroll
  for (int pt = 0; pt < 16; ++pt) {
    #pragma unroll
    for (int j = 0; j < 4; ++j) {
      int t = w * 16 + g * 4 + j;
      int p = pt * 16 + cl;
      float xv = bf2f(*(const u16*)((const char*)xs + xs_addr(t, p)));
      float v = acc[pt][j] + Dv * xv;
      y[(row0 + t) * DINNER + h * HEADDIM + p] = f2bf(v);
    }
  }
}

// ---------------- layernorm (bf16 in) -> bf16 ----------------
__global__ __launch_bounds__(256) void ln_kernel(const u16* __restrict__ y,
                                                 const float* __restrict__ gamma,
                                                 const float* __restrict__ beta,
                                                 u16* __restrict__ nrm) {
  const int row = blockIdx.x;
  const int t = threadIdx.x;
  const u16* yr = y + (size_t)row * DINNER;
  short8 v = *(const short8*)(yr + t * 8);
  float f[8];
  float s = 0.f, ss = 0.f;
  #pragma unroll
  for (int j = 0; j < 8; ++j) {
    f[j] = bf2f((u16)v[j]);
    s += f[j]; ss += f[j] * f[j];
  }
  #pragma unroll
  for (int o = 1; o < 64; o <<= 1) { s += __shfl_xor(s, o); ss += __shfl_xor(ss, o); }
  __shared__ float rs[4], rss[4];
  const int wid = t >> 6;
  if ((t & 63) == 0) { rs[wid] = s; rss[wid] = ss; }
  __syncthreads();
  s = rs[0] + rs[1] + rs[2] + rs[3];
  ss = rss[0] + rss[1] + rss[2] + rss[3];
  float mu = s * (1.f / DINNER);
  float var = ss * (1.f / DINNER) - mu * mu;
  float inv = rsqrtf(var + 1e-5f);
  float4 g0 = ((const float4*)gamma)[t * 2], g1 = ((const float4*)gamma)[t * 2 + 1];
  float4 b0 = ((const float4*)beta)[t * 2], b1 = ((const float4*)beta)[t * 2 + 1];
  short8 o;
  o[0] = (short)f2bf((f[0] - mu) * inv * g0.x + b0.x);
  o[1] = (short)f2bf((f[1] - mu) * inv * g0.y + b0.y);
  o[2] = (short)f2bf((f[2] - mu) * inv * g0.z + b0.z);
  o[3] = (short)f2bf((f[3] - mu) * inv * g0.w + b0.w);
  o[4] = (short)f2bf((f[4] - mu) * inv * g1.x + b1.x);
  o[5] = (short)f2bf((f[5] - mu) * inv * g1.y + b1.y);
  o[6] = (short)f2bf((f[6] - mu) * inv * g1.z + b1.z);
  o[7] = (short)f2bf((f[7] - mu) * inv * g1.w + b1.w);
  *(short8*)(nrm + (size_t)row * DINNER + t * 8) = o;
}

// ---------------- host ----------------
extern "C" void kernel_launch(void* const* d_in, const int* in_sizes, int n_in,
                              void* d_out, int out_size, void* d_ws, size_t ws_size,
                              hipStream_t stream) {
  (void)in_sizes; (void)n_in; (void)out_size; (void)ws_size;
  const float* u       = (const float*)d_in[0];
  const float* W_in    = (const float*)d_in[1];
  const float* conv_w  = (const float*)d_in[2];
  const float* conv_b  = (const float*)d_in[3];
  const float* dt_bias = (const float*)d_in[4];
  const float* A_log   = (const float*)d_in[5];
  const float* D_par   = (const float*)d_in[6];
  const float* ln_g    = (const float*)d_in[7];
  const float* ln_b    = (const float*)d_in[8];
  const float* W_gate  = (const float*)d_in[9];
  const float* b_gate  = (const float*)d_in[10];
  const float* W_out   = (const float*)d_in[11];
  float* out = (float*)d_out;

  size_t off = 0;
  auto take = [&](size_t bytes) -> char* {
    char* p = (char*)d_ws + off;
    off = (off + bytes + 255) & ~(size_t)255;
    return p;
  };
  u16* u16b  = (u16*)take((size_t)MROWS * DMODEL * 2);          // dead after gemmA
  u16* Wp    = (u16*)take((size_t)NPAD * DMODEL * 2);           // dead after gemmA
  u16* Wg    = (u16*)take((size_t)DINNER * DINNER * 2);         // dead after gemm1
  u16* Wo    = (u16*)take((size_t)DMODEL * 2 * DINNER * 2);
  u16* zx    = (u16*)take((size_t)MROWS * NPAD * 2);            // 52.4 MB
  u16* xc    = (u16*)take((size_t)MROWS * DINNER * 2);
  float* bcb = (float*)take((size_t)MROWS * 32 * 4);
  float* dtb = (float*)take((size_t)MROWS * NHEADS * 4);
  float* lcbuf = (float*)take((size_t)BH * NCHUNK * 64 * 4);
  u16* nrm   = (u16*)take((size_t)MROWS * DINNER * 2);
  u16* hcat  = (u16*)take((size_t)MROWS * 2 * DINNER * 2);

  float* Sbuf  = (float*)u16b;                                   // 8 MB (u16b dead)
  u16*   y     = zx;                                             // 16 MB
  float* Sprev = (float*)((char*)zx + (size_t)16 * 1024 * 1024); // 8 MB

  cvt_all<<<4096, 256, 0, stream>>>(u, W_gate, W_out, W_in, u16b, Wg, Wo, Wp);

  // gemm0: 256x256 tiles, grid 16x25=400
  gemmA<<<dim3(MROWS / 256, NPAD / 256), 512, 0, stream>>>(
      u16b, Wp, DMODEL, DMODEL, NPAD, zx);

  prep_kernel<<<NB_CONV + NB_MLP + NB_DT, 256, 0, stream>>>(
      zx, conv_w, conv_b, xc, bcb, hcat, dt_bias, dtb);

  ssd_state<<<BH * NCHUNK, 256, 0, stream>>>(xc, bcb, dtb, A_log, Sbuf, lcbuf);
  ssd_combine<<<BH * 16, 256, 0, stream>>>(Sbuf, lcbuf, Sprev);
  ssd_out<<<BH * NCHUNK, 256, 0, stream>>>(xc, bcb, dtb, lcbuf, Sprev, D_par, y);

  ln_kernel<<<MROWS, 256, 0, stream>>>(y, ln_g, ln_b, nrm);

  // gemm1: 256x128 tiles, ring-3, unsplit K, fused gate; grid 16x16 (MAP 1)
  gemmB<1, 1><<<dim3(MROWS / 256, DINNER / 128), 512, 0, stream>>>(
      nrm, Wg, DINNER, DINNER, 0, hcat, b_gate, nrm);

  // gemm2: 128x128 tiles, ring-3, unsplit K=4096, fp32 out; grid 32x8=256
  gemmC<<<dim3(MROWS / 128, DMODEL / 128), 512, 0, stream>>>(
      hcat, Wo, 2 * DINNER, 2 * DINNER, DMODEL, out);
}